// Round 12
// baseline (447.942 us; speedup 1.0000x reference)
//
#include <hip/hip_runtime.h>
#include <math.h>

// Problem constants
#define BB   128
#define NN   128
#define LL   248
#define DD   768
#define HH   8
#define HDh  96
#define HIDN 256
#define MROWS (BB*NN)   // 16384
#define MB_   (1u<<20)
#define KVLD 1536       // fused K|V row stride (elements)

typedef unsigned short u16;
typedef unsigned int   u32;
typedef __attribute__((ext_vector_type(8))) short s16x8;
typedef __attribute__((ext_vector_type(4))) float f32x4;

// ---------------------------------------------------------------------------
// helpers
// ---------------------------------------------------------------------------
__device__ __forceinline__ u16 f2bf(float x) {
    u32 u = __float_as_uint(x);
    u32 r = u + 0x7fffu + ((u >> 16) & 1u);
    return (u16)(r >> 16);
}
__device__ __forceinline__ float bf2f(u16 h) {
    return __uint_as_float(((u32)h) << 16);
}
__device__ __forceinline__ void gload16(const void* g, void* l) {
    __builtin_amdgcn_global_load_lds(
        (const __attribute__((address_space(1))) void*)g,
        (__attribute__((address_space(3))) void*)l, 16, 0, 0);
}

template<int NT>
__device__ __forceinline__ float breduce_sum(float v, float* red) {
    const int tid = threadIdx.x;
    red[tid] = v; __syncthreads();
#pragma unroll
    for (int o = NT / 2; o > 0; o >>= 1) {
        if (tid < o) red[tid] += red[tid + o];
        __syncthreads();
    }
    float r = red[0]; __syncthreads();
    return r;
}
__device__ __forceinline__ double breduce_sum_d256(double v, double* red) {
    const int tid = threadIdx.x;
    red[tid] = v; __syncthreads();
#pragma unroll
    for (int o = 128; o > 0; o >>= 1) {
        if (tid < o) red[tid] += red[tid + o];
        __syncthreads();
    }
    double r = red[0]; __syncthreads();
    return r;
}

// ---------------------------------------------------------------------------
// ONE prep dispatch: 5 weight transposes (4416 blocks) | clip_n (256 blocks)
// | text/q elementwise + cpos + zbias (2048 blocks, UNIT-STRIDE float4 loads
//   + uint2 bf16 stores: every VMEM instruction fully coalesced)
// ---------------------------------------------------------------------------
#define TEXT_F4 (BB*LL*DD/4)     // 6094848  (multiple of 512)
#define Q_F4    (MROWS*(DD/4))   // 3145728  (multiple of 512)
__global__ __launch_bounds__(256)
void prep_all_kernel(const float* __restrict__ ctx_W, u16* __restrict__ ctx_Wt,
                     const float* __restrict__ in_W,  u16* __restrict__ in_Wt,
                     const float* __restrict__ out_W, u16* __restrict__ out_Wt,
                     const float* __restrict__ r1_W,  u16* __restrict__ r1_Wt,
                     const float* __restrict__ r2_W,  u16* __restrict__ r2_Wt,
                     const float* __restrict__ text,  u16* __restrict__ textb,
                     const float* __restrict__ wf,    u16* __restrict__ qb,
                     const int* __restrict__ wpos,    int* __restrict__ cpos,
                     const float* __restrict__ pe,    u16* __restrict__ clipb,
                     float* __restrict__ zbias) {
    __shared__ float smem[32 * 33];
    int bid = blockIdx.x;
    const int tid = threadIdx.x;

    if (bid < 4416) {
        // ---- weight transposes ----
        const float* src; u16* dst; int C;
        if (bid < 1728)      { src = ctx_W; dst = ctx_Wt; C = 768;  }
        else if (bid < 3456) { src = in_W;  dst = in_Wt;  C = 2304; bid -= 1728; }
        else if (bid < 4032) { src = out_W; dst = out_Wt; C = 768;  bid -= 3456; }
        else if (bid < 4224) { src = r1_W;  dst = r1_Wt;  C = 256;  bid -= 4032; }
        else                 { src = r2_W;  dst = r2_Wt;  C = 768;  bid -= 4224; }
        const int R = (C == 768) ? ((dst == ctx_Wt) ? 2304 : ((dst == out_Wt) ? 768 : 256))
                                 : 768;
        const int ct = C >> 5;
        const int r0 = (bid / ct) * 32, c0 = (bid % ct) * 32;
        const int tx = tid & 31, ty = tid >> 5;
#pragma unroll
        for (int i = 0; i < 32; i += 8)
            smem[(ty + i) * 33 + tx] = src[(size_t)(r0 + ty + i) * C + c0 + tx];
        __syncthreads();
#pragma unroll
        for (int i = 0; i < 32; i += 8)
            dst[(size_t)(c0 + ty + i) * R + r0 + tx] = f2bf(smem[tx * 33 + ty + i]);
    } else if (bid < 4672) {
        // ---- clip_n bf16 [256][768], rows >= 248 zero ----
        const int l = bid - 4416;
        if (l >= LL) {
            for (int j = 0; j < 3; ++j) clipb[(size_t)l * DD + tid + j * 256] = 0;
            return;
        }
        float t[3]; float q = 0.f;
#pragma unroll
        for (int j = 0; j < 3; ++j) {
            t[j] = pe[(size_t)l * DD + tid + j * 256];
            q = fmaf(t[j], t[j], q);
        }
        q = breduce_sum<256>(q, smem);
        float inv = 1.f / fmaxf(sqrtf(q), 1e-12f);
#pragma unroll
        for (int j = 0; j < 3; ++j)
            clipb[(size_t)l * DD + tid + j * 256] = f2bf(t[j] * inv);
    } else {
        // ---- elementwise conversions, unit-stride (fully coalesced) ----
        const int ebid = bid - 4672;
        if (ebid == 0) {
            for (int r = tid; r < MROWS; r += 256) {
                int w = wpos[r];
                cpos[r] = w < 0 ? 0 : (w > LL - 1 ? LL - 1 : w);
            }
            if (tid < 256) zbias[tid] = 0.f;
        }
        const int lane = tid & 63;
        const int wid = ebid * 4 + (tid >> 6);       // 0..8191
        const int NCHUNK = (TEXT_F4 + Q_F4) / 512;   // 18048
        for (int c = wid; c < NCHUNK; c += 8192) {
            const int base = c * 512;                // float4 index
            if (base < TEXT_F4) {
                const float4* sp = (const float4*)text;
                uint2* op = (uint2*)textb;
                float4 v[8];
#pragma unroll
                for (int j = 0; j < 8; ++j)
                    v[j] = sp[(size_t)base + j * 64 + lane];
#pragma unroll
                for (int j = 0; j < 8; ++j) {
                    uint2 o;
                    o.x = (u32)f2bf(v[j].x) | ((u32)f2bf(v[j].y) << 16);
                    o.y = (u32)f2bf(v[j].z) | ((u32)f2bf(v[j].w) << 16);
                    op[(size_t)base + j * 64 + lane] = o;
                }
            } else {
                const int qb4 = base - TEXT_F4;
                const float4* sp = (const float4*)wf;
                uint2* op = (uint2*)qb;
                float4 v[8]; float vfm[8];
#pragma unroll
                for (int j = 0; j < 8; ++j)
                    v[j] = sp[(size_t)qb4 + j * 64 + lane];
#pragma unroll
                for (int j = 0; j < 8; ++j)
                    vfm[j] = (wpos[(qb4 + j * 64 + lane) / 192] != -1) ? 1.f : 0.f;
#pragma unroll
                for (int j = 0; j < 8; ++j) {
                    uint2 o;
                    o.x = (u32)f2bf(v[j].x * vfm[j]) | ((u32)f2bf(v[j].y * vfm[j]) << 16);
                    o.y = (u32)f2bf(v[j].z * vfm[j]) | ((u32)f2bf(v[j].w * vfm[j]) << 16);
                    op[(size_t)qb4 + j * 64 + lane] = o;
                }
            }
        }
    }
}

// ---------------------------------------------------------------------------
// bf16 MFMA GEMM, BK=64: 128x128 tile, 256 threads (4 waves), 32 MFMA/K-step.
// XCD-aware block swizzle (T1). Swizzle involution for 128B rows:
// write source chunk ce=((l&7)^(l>>3))<<3, read chunk (lg^(la&7)) (^32 for kk=1).
// ---------------------------------------------------------------------------
template<int GATHER, int CBF16, int MASK>
__global__ __launch_bounds__(256)
void gemm_bt(const u16* __restrict__ A,
             const u16* __restrict__ TXT,
             const int* __restrict__ cpos,
             const u16* __restrict__ Bt,
             const float* __restrict__ bias,
             void* __restrict__ Cout, int ldc, int K,
             const int* __restrict__ wpos) {
    __shared__ __align__(16) u16 Alds[128 * 64];   // 16 KB
    __shared__ __align__(16) u16 Blds[128 * 64];   // 16 KB
    const int tid = threadIdx.x;
    const int l = tid & 63, wv = tid >> 6;

    // XCD swizzle
    const int gx  = gridDim.x;
    const int hw  = blockIdx.y * gx + blockIdx.x;
    const int nwg = gx * gridDim.y;
    const int cpx = nwg >> 3;
    const int lin = (hw & 7) * cpx + (hw >> 3);
    const int m0 = (lin / gx) * 128, n0 = (lin % gx) * 128;

    const int rw = wv * 8 + (l >> 3);              // 0..31 within issue
    const int ce = ((l & 7) ^ (l >> 3)) << 3;      // inverse-swizzled source col
    u16* Ad0 = Alds + wv * 512;
    u16* Bd0 = Blds + wv * 512;

    const int wm = (wv >> 1) * 64, wn = (wv & 1) * 64;
    const int la = l & 15, lg = l >> 4;

    int aoff[4], boff[4];
#pragma unroll
    for (int m = 0; m < 4; ++m) {
        int ra = wm + m * 16 + la;
        aoff[m] = ra * 64 + (((lg ^ (la & 7)) << 3));
        int rb = wn + m * 16 + la;
        boff[m] = rb * 64 + (((lg ^ (la & 7)) << 3));
    }

    const u16* pb[4];
#pragma unroll
    for (int i = 0; i < 4; ++i)
        pb[i] = Bt + (size_t)(n0 + rw + i * 32) * K + ce;

    f32x4 acc[4][4] = {};

    auto do_step = [&](const u16* a0, const u16* a1, const u16* a2, const u16* a3,
                       const u16* b0, const u16* b1, const u16* b2, const u16* b3) {
        gload16(a0, Ad0);
        gload16(a1, Ad0 + 2048);
        gload16(a2, Ad0 + 4096);
        gload16(a3, Ad0 + 6144);
        gload16(b0, Bd0);
        gload16(b1, Bd0 + 2048);
        gload16(b2, Bd0 + 4096);
        gload16(b3, Bd0 + 6144);
        __syncthreads();
#pragma unroll
        for (int kk = 0; kk < 2; ++kk) {
            const int kx = kk << 5;
            s16x8 af[4], bf[4];
#pragma unroll
            for (int m = 0; m < 4; ++m) af[m] = *(const s16x8*)(Alds + (aoff[m] ^ kx));
#pragma unroll
            for (int n = 0; n < 4; ++n) bf[n] = *(const s16x8*)(Blds + (boff[n] ^ kx));
#pragma unroll
            for (int m = 0; m < 4; ++m)
#pragma unroll
                for (int n = 0; n < 4; ++n)
                    acc[m][n] = __builtin_amdgcn_mfma_f32_16x16x32_bf16(
                        af[m], bf[n], acc[m][n], 0, 0, 0);
        }
        __syncthreads();
    };

    if constexpr (GATHER) {
        int gb[4], gc[4];
#pragma unroll
        for (int i = 0; i < 4; ++i) {
            int g = m0 + rw + i * 32;
            gb[i] = g >> 7;
            gc[i] = cpos[g];
        }
#pragma unroll 1
        for (int w = 0; w < 3; ++w) {
            const u16* pa[4];
#pragma unroll
            for (int i = 0; i < 4; ++i) {
                int p = gc[i] + w - 1;
                p = p < 0 ? 0 : (p > LL - 1 ? LL - 1 : p);
                pa[i] = TXT + ((size_t)(gb[i] * LL + p)) * DD + ce;
            }
            const u16* b0 = pb[0] + w * DD; const u16* b1 = pb[1] + w * DD;
            const u16* b2 = pb[2] + w * DD; const u16* b3 = pb[3] + w * DD;
#pragma unroll 1
            for (int kt = 0; kt < 12; ++kt)
                do_step(pa[0] + kt * 64, pa[1] + kt * 64, pa[2] + kt * 64, pa[3] + kt * 64,
                        b0 + kt * 64, b1 + kt * 64, b2 + kt * 64, b3 + kt * 64);
        }
    } else {
        const u16* pa[4];
#pragma unroll
        for (int i = 0; i < 4; ++i)
            pa[i] = A + (size_t)(m0 + rw + i * 32) * K + ce;
        const int nk = K >> 6;
#pragma unroll 1
        for (int kt = 0; kt < nk; ++kt)
            do_step(pa[0] + (kt << 6), pa[1] + (kt << 6), pa[2] + (kt << 6), pa[3] + (kt << 6),
                    pb[0] + (kt << 6), pb[1] + (kt << 6), pb[2] + (kt << 6), pb[3] + (kt << 6));
    }

#pragma unroll
    for (int m = 0; m < 4; ++m) {
        const int rb = m0 + wm + m * 16 + lg * 4;
        float vf[4];
        if constexpr (MASK) {
#pragma unroll
            for (int r = 0; r < 4; ++r) vf[r] = (wpos[rb + r] != -1) ? 1.f : 0.f;
        }
#pragma unroll
        for (int n = 0; n < 4; ++n) {
            const int col = n0 + wn + n * 16 + la;
            const float bv = bias[col];
#pragma unroll
            for (int r = 0; r < 4; ++r) {
                float o = acc[m][n][r] + bv;
                if constexpr (MASK) o *= vf[r];
                if constexpr (CBF16)
                    ((u16*)Cout)[(size_t)(rb + r) * ldc + col] = f2bf(o);
                else
                    ((float*)Cout)[(size_t)(rb + r) * ldc + col] = o;
            }
        }
    }
}

// ---------------------------------------------------------------------------
// MFMA attention: one block per (b,h), 512 threads = 8 waves, 16 q-rows/wave.
// K/V from fused kv buffer (row stride KVLD; K cols [0,768), V cols [768,1536)).
// ---------------------------------------------------------------------------
__global__ __launch_bounds__(512)
void attn_mfma_kernel(const u16* __restrict__ qp, const u16* __restrict__ kvb,
                      u16* __restrict__ ao) {
    __shared__ __align__(16) u16 K_lds[128 * 96];    // 24 KB
    __shared__ __align__(16) u16 Vt_lds[96 * 128];   // 24 KB
    __shared__ __align__(16) u16 P_lds[128 * 128];   // 32 KB
    const int bh = blockIdx.x;
    const int b = bh >> 3, h = bh & 7;
    const int tid = threadIdx.x;
    const int l = tid & 63, wv = tid >> 6;
    const int la = l & 15, lg = l >> 4;
    const float scale = 0.10206207261596575f;  // 1/sqrt(96)

    const size_t qbase  = ((size_t)b * NN) * DD + h * HDh;
    const size_t kvbase = ((size_t)b * NN) * KVLD + h * HDh;

#pragma unroll
    for (int i = 0; i < 3; ++i) {
        int f = i * 8192 + wv * 1024 + l * 16;
        int row = f / 192;
        int inner = f - row * 192;
        gload16((const char*)(kvb + kvbase + (size_t)row * KVLD) + inner,
                (char*)K_lds + f);
    }

    uint4 vchunk[3]; int vkey[3], vd0[3];
#pragma unroll
    for (int i = 0; i < 3; ++i) {
        int c = tid + i * 512;
        int key = c / 12, dc = c - key * 12;
        vkey[i] = key; vd0[i] = dc * 8;
        vchunk[i] = *(const uint4*)(kvb + kvbase + (size_t)key * KVLD + DD + dc * 8);
    }

    const int q0 = wv * 16;
    s16x8 qf[3];
#pragma unroll
    for (int kt = 0; kt < 3; ++kt)
        qf[kt] = *(const s16x8*)(qp + qbase + (size_t)(q0 + la) * DD + kt * 32 + lg * 8);

#pragma unroll
    for (int i = 0; i < 3; ++i) {
        const u16* e = (const u16*)&vchunk[i];
#pragma unroll
        for (int j = 0; j < 8; ++j) {
            int d = vd0[i] + j;
            int byte = ((d * 128 + vkey[i]) * 2) ^ ((d & 7) << 4);
            *(u16*)((char*)Vt_lds + byte) = e[j];
        }
    }
    __syncthreads();

    f32x4 sacc[8] = {};
#pragma unroll
    for (int kt = 0; kt < 3; ++kt) {
#pragma unroll
        for (int nf = 0; nf < 8; ++nf) {
            s16x8 bfr = *(const s16x8*)(K_lds + (nf * 16 + la) * 96 + kt * 32 + lg * 8);
            sacc[nf] = __builtin_amdgcn_mfma_f32_16x16x32_bf16(qf[kt], bfr, sacc[nf], 0, 0, 0);
        }
    }

#pragma unroll
    for (int r = 0; r < 4; ++r) {
        float m = -1e30f;
#pragma unroll
        for (int nf = 0; nf < 8; ++nf) m = fmaxf(m, sacc[nf][r]);
#pragma unroll
        for (int o = 8; o > 0; o >>= 1) m = fmaxf(m, __shfl_xor(m, o, 64));
        m *= scale;
        float p[8]; float s = 0.f;
#pragma unroll
        for (int nf = 0; nf < 8; ++nf) { p[nf] = expf(sacc[nf][r] * scale - m); s += p[nf]; }
#pragma unroll
        for (int o = 8; o > 0; o >>= 1) s += __shfl_xor(s, o, 64);
        const float inv = 1.f / s;
        const int q = q0 + lg * 4 + r;
#pragma unroll
        for (int nf = 0; nf < 8; ++nf) {
            int byte = ((q * 128 + nf * 16 + la) * 2) ^ ((q & 7) << 4);
            *(u16*)((char*)P_lds + byte) = f2bf(p[nf] * inv);
        }
    }
    __syncthreads();

    f32x4 oacc[6] = {};
#pragma unroll
    for (int kk = 0; kk < 4; ++kk) {
        const int qrow = q0 + la;
        int abyte = ((qrow * 128 + kk * 32 + lg * 8) * 2) ^ ((qrow & 7) << 4);
        s16x8 af = *(const s16x8*)((char*)P_lds + abyte);
#pragma unroll
        for (int nf = 0; nf < 6; ++nf) {
            const int d = nf * 16 + la;
            int bbyte = ((d * 128 + kk * 32 + lg * 8) * 2) ^ ((d & 7) << 4);
            s16x8 bfr = *(const s16x8*)((char*)Vt_lds + bbyte);
            oacc[nf] = __builtin_amdgcn_mfma_f32_16x16x32_bf16(af, bfr, oacc[nf], 0, 0, 0);
        }
    }

#pragma unroll
    for (int nf = 0; nf < 6; ++nf) {
#pragma unroll
        for (int r = 0; r < 4; ++r) {
            const int q = q0 + lg * 4 + r;
            ao[qbase + (size_t)q * DD + nf * 16 + la] = f2bf(oacc[nf][r]);
        }
    }
}

// ---------------------------------------------------------------------------
// x = layernorm(q(bf16) + attn_out(bf16); cn_g, cn_b) * vf -> bf16
// ---------------------------------------------------------------------------
__global__ __launch_bounds__(256)
void ln768_kernel(const u16* __restrict__ qb, const u16* __restrict__ at,
                  const int* __restrict__ wpos, const float* __restrict__ g,
                  const float* __restrict__ bta, u16* __restrict__ xout) {
    __shared__ float red[256];
    const int r = blockIdx.x, tid = threadIdx.x;
    const float vf = (wpos[r] != -1) ? 1.f : 0.f;
    float t[3]; float s = 0.f, q = 0.f;
#pragma unroll
    for (int j = 0; j < 3; ++j) {
        int d = tid + j * 256;
        t[j] = bf2f(qb[(size_t)r * DD + d]) + bf2f(at[(size_t)r * DD + d]);
        s += t[j];
        q = fmaf(t[j], t[j], q);
    }
    s = breduce_sum<256>(s, red);
    q = breduce_sum<256>(q, red);
    float mean = s * (1.f / DD);
    float var  = q * (1.f / DD) - mean * mean;
    float inv  = 1.f / sqrtf(var + 1e-5f);
#pragma unroll
    for (int j = 0; j < 3; ++j) {
        int d = tid + j * 256;
        xout[(size_t)r * DD + d] = f2bf(((t[j] - mean) * inv * g[d] + bta[d]) * vf);
    }
}

// ---------------------------------------------------------------------------
// h = layernorm(gelu_exact(g1 bf16); ln_g, ln_b) -> bf16   (row = 256)
// ---------------------------------------------------------------------------
__global__ __launch_bounds__(256)
void ln256_gelu_kernel(const u16* __restrict__ g1, const float* __restrict__ lg,
                       const float* __restrict__ lb, u16* __restrict__ hout) {
    __shared__ float red[256];
    const int r = blockIdx.x, tid = threadIdx.x;
    float v  = bf2f(g1[(size_t)r * HIDN + tid]);
    float ge = 0.5f * v * (1.f + erff(v * 0.7071067811865475f));
    float s = breduce_sum<256>(ge, red);
    float q = breduce_sum<256>(ge * ge, red);
    float mean = s * (1.f / HIDN);
    float var  = q * (1.f / HIDN) - mean * mean;
    float inv  = 1.f / sqrtf(var + 1e-5f);
    hout[(size_t)r * HIDN + tid] = f2bf((ge - mean) * inv * lg[tid] + lb[tid]);
}

// ---------------------------------------------------------------------------
// L2-normalize rope (bf16 in) -> rnb bf16
// ---------------------------------------------------------------------------
__global__ __launch_bounds__(256)
void norm_rnb_kernel(const u16* __restrict__ ropeb, u16* __restrict__ rnb) {
    __shared__ float red[256];
    const int r = blockIdx.x, tid = threadIdx.x;
    float t[3]; float q = 0.f;
#pragma unroll
    for (int j = 0; j < 3; ++j) {
        t[j] = bf2f(ropeb[(size_t)r * DD + tid + j * 256]);
        q = fmaf(t[j], t[j], q);
    }
    q = breduce_sum<256>(q, red);
    float inv = 1.f / fmaxf(sqrtf(q), 1e-12f);
#pragma unroll
    for (int j = 0; j < 3; ++j)
        rnb[(size_t)r * DD + tid + j * 256] = f2bf(t[j] * inv);
}

// ---------------------------------------------------------------------------
// emb full-coverage writer (replaces memset + scatter):
// one block per (b,l). Binary-search l in sorted word_pos[b,:].
// ---------------------------------------------------------------------------
__global__ __launch_bounds__(256)
void emb_full_kernel(const u16* __restrict__ ropeb, const float* __restrict__ pe,
                     const int* __restrict__ wpos, float* __restrict__ emb) {
    const int bl = blockIdx.x;
    const int b = bl / LL, l = bl - b * LL;
    const int tid = threadIdx.x;
    const int* wp = wpos + b * NN;
    int lo = 0, hi = NN - 1, found = -1;
    while (lo <= hi) {
        int mid = (lo + hi) >> 1;
        int v = wp[mid];
        if (v == l) { found = mid; break; }
        if (v < l) lo = mid + 1; else hi = mid - 1;
    }
    float* dst = emb + (size_t)bl * DD;
    if (found >= 0) {
        const u16* rr = ropeb + (size_t)(b * NN + found) * DD;
#pragma unroll
        for (int j = 0; j < 3; ++j) {
            int d = tid + j * 256;
            dst[d] = 0.8f * pe[(size_t)l * DD + d] + 0.2f * bf2f(rr[d]);
        }
    } else {
#pragma unroll
        for (int j = 0; j < 3; ++j)
            dst[tid + j * 256] = 0.f;
    }
}

// ---------------------------------------------------------------------------
// KL from precomputed logits. One WAVE per row, 4 rows/block.
// ---------------------------------------------------------------------------
__global__ __launch_bounds__(256)
void kl_lite_kernel(const float* __restrict__ logits, const int* __restrict__ wpos,
                    const float* __restrict__ pos_temp, float* __restrict__ klp) {
    const int row = blockIdx.x * 4 + (threadIdx.x >> 6);
    const int l = threadIdx.x & 63;
    const float invt = 1.f / fmaxf(pos_temp[0], 0.001f);
    const float* lrow = logits + (size_t)row * 256;

    float lg[4];
#pragma unroll
    for (int q = 0; q < 4; ++q) {
        int c = l + q * 64;
        lg[q] = (c < LL) ? lrow[c] * invt : -1e30f;
    }
    float m = fmaxf(fmaxf(lg[0], lg[1]), fmaxf(lg[2], lg[3]));
#pragma unroll
    for (int o = 32; o > 0; o >>= 1) m = fmaxf(m, __shfl_xor(m, o, 64));

    float S = 0.f;
#pragma unroll
    for (int q = 0; q < 4; ++q) S += expf(lg[q] - m);
#pragma unroll
    for (int o = 32; o > 0; o >>= 1) S += __shfl_xor(S, o, 64);
    const float logZ = m + logf(S);

    const int wr = wpos[row];
    const bool valid = (wr != -1);
    const int wp = wr < 0 ? 0 : (wr > LL - 1 ? LL - 1 : wr);

    float targ[4]; float tsum = 0.f;
#pragma unroll
    for (int q = 0; q < 4; ++q) {
        int c = l + q * 64;
        float dl = (float)c - (float)wp;
        targ[q] = (c < LL) ? expf(-dl * dl * 0.125f) : 0.f;
        tsum += targ[q];
    }
#pragma unroll
    for (int o = 32; o > 0; o >>= 1) tsum += __shfl_xor(tsum, o, 64);
    const float tden = 1.f / (tsum + 1e-12f);

    float c_ = 0.f;
#pragma unroll
    for (int q = 0; q < 4; ++q) {
        float tn = targ[q] * tden;
        if (valid && tn > 0.f) c_ += tn * (logf(tn) - (lg[q] - logZ));
    }
#pragma unroll
    for (int o = 32; o > 0; o >>= 1) c_ += __shfl_xor(c_, o, 64);
    if (l == 0) klp[row] = c_;
}

// ---------------------------------------------------------------------------
// rel head via MFMA Gram: one block per (b, j-half). 512 threads = 8 waves.
// ---------------------------------------------------------------------------
__global__ __launch_bounds__(512)
void rel_mfma_kernel(const u16* __restrict__ rnb, const int* __restrict__ wpos,
                     float* __restrict__ rel_part, float* __restrict__ vm2_part) {
    __shared__ __align__(16) u16 T[128 * 32];   // 8 KB
    __shared__ float red[512];
    const int blk = blockIdx.x;
    const int b = blk >> 1, jh = blk & 1;
    const int tid = threadIdx.x;
    const int l = tid & 63, wv = tid >> 6;
    const int la = l & 15, lg = l >> 4;

    const int f = wv * 1024 + l * 16;
    const int rA = f >> 6;
    const int cb = (f & 63) ^ (((rA >> 1) & 3) << 4);
    const int ce = cb >> 1;
    const u16* src = rnb + ((size_t)(b * NN + rA)) * DD + ce;
    u16* dst = T + wv * 512;

    const int ra = wv * 16 + la;
    const int aoff = ra * 32 + ((lg * 8) ^ (((ra >> 1) & 3) << 3));
    int boff[4];
#pragma unroll
    for (int nf = 0; nf < 4; ++nf) {
        int rb = jh * 64 + nf * 16 + la;
        boff[nf] = rb * 32 + ((lg * 8) ^ (((rb >> 1) & 3) << 3));
    }

    f32x4 acc[4] = {};
    for (int kt = 0; kt < 24; ++kt) {
        gload16(src + kt * 32, dst);
        __syncthreads();
        s16x8 a = *(const s16x8*)(T + aoff);
        s16x8 bf_[4];
#pragma unroll
        for (int nf = 0; nf < 4; ++nf) bf_[nf] = *(const s16x8*)(T + boff[nf]);
#pragma unroll
        for (int nf = 0; nf < 4; ++nf)
            acc[nf] = __builtin_amdgcn_mfma_f32_16x16x32_bf16(a, bf_[nf], acc[nf], 0, 0, 0);
        __syncthreads();
    }

    float wif[4], vi[4];
#pragma unroll
    for (int r = 0; r < 4; ++r) {
        int wi = wpos[b * NN + wv * 16 + lg * 4 + r];
        vi[r] = (wi != -1) ? 1.f : 0.f;
        wif[r] = (float)(wi < 0 ? 0 : (wi > LL - 1 ? LL - 1 : wi));
    }
    float csum = 0.f, msum = 0.f;
#pragma unroll
    for (int nf = 0; nf < 4; ++nf) {
        int wj = wpos[b * NN + jh * 64 + nf * 16 + la];
        float vj = (wj != -1) ? 1.f : 0.f;
        float wjf = (float)(wj < 0 ? 0 : (wj > LL - 1 ? LL - 1 : wj));
#pragma unroll
        for (int r = 0; r < 4; ++r) {
            float sim = (acc[nf][r] + 1.f) * 0.5f;
            float ts  = 1.f - fabsf(wif[r] - wjf) * (1.f / (float)LL);
            float m2  = vi[r] * vj;
            float df  = m2 * (sim - ts);
            csum += df * df;
            msum += m2;
        }
    }
    csum = breduce_sum<512>(csum, red);
    msum = breduce_sum<512>(msum, red);
    if (tid == 0) { rel_part[blk] = csum; vm2_part[blk] = msum; }
}

// ---------------------------------------------------------------------------
// Final deterministic fp64 reduction
// ---------------------------------------------------------------------------
__global__ __launch_bounds__(256)
void final_kernel(const float* __restrict__ klp, const float* __restrict__ relp,
                  const float* __restrict__ vmp, const int* __restrict__ wpos,
                  float* __restrict__ outs) {
    __shared__ double rd[256];
    const int tid = threadIdx.x;
    double kl = 0.0, rel = 0.0, vm = 0.0, nv = 0.0;
    for (int r = tid; r < MROWS; r += 256) {
        kl += (double)klp[r];
        nv += (wpos[r] != -1) ? 1.0 : 0.0;
    }
    if (tid < 256) {
        rel += (double)relp[tid];
        vm  += (double)vmp[tid];
    }
    kl  = breduce_sum_d256(kl, rd);
    rel = breduce_sum_d256(rel, rd);
    vm  = breduce_sum_d256(vm, rd);
    nv  = breduce_sum_d256(nv, rd);
    if (tid == 0) {
        float klf  = (float)(kl / (nv + 1e-12));
        float relf = (float)(rel / (vm + 1e-12));
        outs[0] = klf + 0.5f * relf;
        outs[1] = klf;
        outs[2] = relf;
    }
}

// ---------------------------------------------------------------------------
extern "C" void kernel_launch(void* const* d_in, const int* in_sizes, int n_in,
                              void* d_out, int out_size, void* d_ws, size_t ws_size,
                              hipStream_t stream) {
    (void)in_sizes; (void)n_in; (void)ws_size; (void)out_size;

    const float* word_feat = (const float*)d_in[0];
    const float* text      = (const float*)d_in[1];
    const int*   wpos      = (const int*)d_in[2];
    const float* ctx_W     = (const float*)d_in[3];
    const float* ctx_b     = (const float*)d_in[4];
    const float* in_W      = (const float*)d_in[5];
    const float* in_b      = (const float*)d_in[6];
    const float* out_W     = (const float*)d_in[7];
    const float* out_b     = (const float*)d_in[8];
    const float* cn_g      = (const float*)d_in[9];
    const float* cn_b      = (const float*)d_in[10];
    const float* r1_W      = (const float*)d_in[11];
    const float* r1_b      = (const float*)d_in[12];
    const float* ln_g      = (const float*)d_in[13];
    const float* ln_b      = (const float*)d_in[14];
    const float* r2_W      = (const float*)d_in[15];
    const float* r2_b      = (const float*)d_in[16];
    const float* pos_emb   = (const float*)d_in[17];
    const float* pos_temp  = (const float*)d_in[18];

    char* W = (char*)d_ws;
    // --- weight/partials area [0, 12MB) ---
    u16*   ctx_Wt = (u16*)(W);
    u16*   in_Wt  = ctx_Wt + (size_t)768 * 2304;
    u16*   out_Wt = in_Wt  + (size_t)2304 * 768;
    u16*   r1_Wt  = out_Wt + (size_t)768 * 768;
    u16*   r2_Wt  = r1_Wt  + (size_t)256 * 768;
    u16*   clipb  = r2_Wt + (size_t)768 * 256;          // [256][768] bf16
    int*   cposb  = (int*)(clipb + (size_t)256 * DD);
    float* klp    = (float*)(cposb + MROWS);
    float* relp   = klp + MROWS;
    float* vmp    = relp + 256;
    float* zbias  = vmp + 256;                           // 256 zero floats
    // --- big regions (lifetimes audited) ---
    u16*   textb  = (u16*)(W + (size_t)12 * MB_);   // 12-58.5, dead after ctx GEMM
    u16*   atoutb = textb;                           // reuse 12-36 (step 5-6)
    float* logits = (float*)(W + (size_t)12 * MB_);  // reuse 12-28 (step 11-12)
    u16*   xb     = (u16*)(W + (size_t)36 * MB_);   // 36-60 (step 6-7)
    u16*   qb     = (u16*)(W + (size_t)60 * MB_);   // 60-84, live until ln768
    u16*   ctxa   = (u16*)(W + (size_t)86 * MB_);   // 86-110 (step 1-3)
    u16*   aob    = ctxa;                            // reuse (step 4-5)
    u16*   rnb    = ctxa;                            // reuse (step 10-13)
    u16*   qpb    = (u16*)(W + (size_t)112 * MB_);  // 112-136 (step 2-4)
    u16*   g1b    = (u16*)(W + (size_t)112 * MB_);  // reuse 112-120 (step 7-8)
    u16*   hb     = (u16*)(W + (size_t)128 * MB_);  // 128-136.4 (step 8-9)
    u16*   kvb    = (u16*)(W + (size_t)138 * MB_);  // 138-186 (step 3-4)
    u16*   ropeb  = kvb;                             // reuse 138-162 (step 9+)

    dim3 blk(256);

    // one prep dispatch: transposes + clip_n + elementwise + cpos + zbias
    prep_all_kernel<<<dim3(4416 + 256 + 2048), blk, 0, stream>>>(
        ctx_W, ctx_Wt, in_W, in_Wt, out_W, out_Wt, r1_W, r1_Wt, r2_W, r2_Wt,
        text, textb, word_feat, qb, wpos, cposb, pos_emb, clipb, zbias);

    dim3 g768(6, 128);
    dim3 g1536(12, 128);
    dim3 g256(2, 128);

    // 1. ctx_anchor = (gather(textb) @ ctx_W + ctx_b) * vf
    gemm_bt<1, 1, 1><<<g768, blk, 0, stream>>>(
        nullptr, textb, cposb, ctx_Wt, ctx_b, ctxa, DD, 3 * DD, wpos);
    // 2. qp
    gemm_bt<0, 1, 0><<<g768, blk, 0, stream>>>(
        qb, nullptr, nullptr, in_Wt, in_b, qpb, DD, DD, nullptr);
    // 3. fused kp|vp
    gemm_bt<0, 1, 0><<<g1536, blk, 0, stream>>>(
        ctxa, nullptr, nullptr, in_Wt + (size_t)768 * 768, in_b + DD, kvb, KVLD, DD, nullptr);
    // 4. MFMA attention -> ao (overwrites ctxa)
    attn_mfma_kernel<<<dim3(BB * HH), dim3(512), 0, stream>>>(qpb, kvb, aob);
    // 5. attn_out = ao @ out_W + out_b (into old text region)
    gemm_bt<0, 1, 0><<<g768, blk, 0, stream>>>(
        aob, nullptr, nullptr, out_Wt, out_b, atoutb, DD, DD, nullptr);
    // 6. x = LN(q + attn_out)*vf  (reads qb bf16)
    ln768_kernel<<<dim3(MROWS), blk, 0, stream>>>(qb, atoutb, wpos, cn_g, cn_b, xb);
    // 7. g1 = x @ r1_W + r1_b -> bf16
    gemm_bt<0, 1, 0><<<g256, blk, 0, stream>>>(
        xb, nullptr, nullptr, r1_Wt, r1_b, g1b, HIDN, DD, nullptr);
    // 8. h = LN(gelu(g1))
    ln256_gelu_kernel<<<dim3(MROWS), blk, 0, stream>>>(g1b, ln_g, ln_b, hb);
    // 9. rope = h @ r2_W + r2_b -> bf16 ropeb
    gemm_bt<0, 1, 0><<<g768, blk, 0, stream>>>(
        hb, nullptr, nullptr, r2_Wt, r2_b, ropeb, DD, HIDN, nullptr);
    // 10. rope -> rnb (bf16 normalized)
    norm_rnb_kernel<<<dim3(MROWS), blk, 0, stream>>>(ropeb, rnb);
    // 11. logits = rope_n @ clip_n^T
    gemm_bt<0, 0, 0><<<g256, blk, 0, stream>>>(
        rnb, nullptr, nullptr, clipb, zbias, logits, 256, DD, nullptr);
    // 12. KL from logits
    kl_lite_kernel<<<dim3(MROWS / 4), blk, 0, stream>>>(logits, wpos, pos_temp, klp);
    // 13. rel via MFMA Gram
    rel_mfma_kernel<<<dim3(BB * 2), dim3(512), 0, stream>>>(rnb, wpos, relp, vmp);
    // 14. emb full-coverage write (replaces memset + scatter)
    emb_full_kernel<<<dim3(BB * LL), blk, 0, stream>>>(
        ropeb, pos_emb, wpos, (float*)d_out);
    // 15. scalars
    final_kernel<<<dim3(1), blk, 0, stream>>>(
        klp, relp, vmp, wpos, (float*)d_out + (size_t)BB * LL * DD);
}

// Round 13
// 433.108 us; speedup vs baseline: 1.0343x; 1.0343x over previous
//
#include <hip/hip_runtime.h>
#include <math.h>

// Problem constants
#define BB   128
#define NN   128
#define LL   248
#define DD   768
#define HH   8
#define HDh  96
#define HIDN 256
#define MROWS (BB*NN)   // 16384
#define MB_   (1u<<20)
#define KVLD 1536       // fused K|V row stride (elements)

typedef unsigned short u16;
typedef unsigned int   u32;
typedef __attribute__((ext_vector_type(8))) short s16x8;
typedef __attribute__((ext_vector_type(4))) float f32x4;

// ---------------------------------------------------------------------------
// helpers
// ---------------------------------------------------------------------------
__device__ __forceinline__ u16 f2bf(float x) {
    u32 u = __float_as_uint(x);
    u32 r = u + 0x7fffu + ((u >> 16) & 1u);
    return (u16)(r >> 16);
}
__device__ __forceinline__ float bf2f(u16 h) {
    return __uint_as_float(((u32)h) << 16);
}
__device__ __forceinline__ void gload16(const void* g, void* l) {
    __builtin_amdgcn_global_load_lds(
        (const __attribute__((address_space(1))) void*)g,
        (__attribute__((address_space(3))) void*)l, 16, 0, 0);
}

template<int NT>
__device__ __forceinline__ float breduce_sum(float v, float* red) {
    const int tid = threadIdx.x;
    red[tid] = v; __syncthreads();
#pragma unroll
    for (int o = NT / 2; o > 0; o >>= 1) {
        if (tid < o) red[tid] += red[tid + o];
        __syncthreads();
    }
    float r = red[0]; __syncthreads();
    return r;
}
__device__ __forceinline__ double breduce_sum_d256(double v, double* red) {
    const int tid = threadIdx.x;
    red[tid] = v; __syncthreads();
#pragma unroll
    for (int o = 128; o > 0; o >>= 1) {
        if (tid < o) red[tid] += red[tid + o];
        __syncthreads();
    }
    double r = red[0]; __syncthreads();
    return r;
}

// ---------------------------------------------------------------------------
// ONE prep dispatch (r12 structure: proven, at its stream ceiling)
// ---------------------------------------------------------------------------
#define TEXT_F4 (BB*LL*DD/4)     // 6094848  (multiple of 512)
#define Q_F4    (MROWS*(DD/4))   // 3145728  (multiple of 512)
__global__ __launch_bounds__(256)
void prep_all_kernel(const float* __restrict__ ctx_W, u16* __restrict__ ctx_Wt,
                     const float* __restrict__ in_W,  u16* __restrict__ in_Wt,
                     const float* __restrict__ out_W, u16* __restrict__ out_Wt,
                     const float* __restrict__ r1_W,  u16* __restrict__ r1_Wt,
                     const float* __restrict__ r2_W,  u16* __restrict__ r2_Wt,
                     const float* __restrict__ text,  u16* __restrict__ textb,
                     const float* __restrict__ wf,    u16* __restrict__ qb,
                     const int* __restrict__ wpos,    int* __restrict__ cpos,
                     const float* __restrict__ pe,    u16* __restrict__ clipb,
                     float* __restrict__ zbias) {
    __shared__ float smem[32 * 33];
    int bid = blockIdx.x;
    const int tid = threadIdx.x;

    if (bid < 4416) {
        const float* src; u16* dst; int C;
        if (bid < 1728)      { src = ctx_W; dst = ctx_Wt; C = 768;  }
        else if (bid < 3456) { src = in_W;  dst = in_Wt;  C = 2304; bid -= 1728; }
        else if (bid < 4032) { src = out_W; dst = out_Wt; C = 768;  bid -= 3456; }
        else if (bid < 4224) { src = r1_W;  dst = r1_Wt;  C = 256;  bid -= 4032; }
        else                 { src = r2_W;  dst = r2_Wt;  C = 768;  bid -= 4224; }
        const int R = (C == 768) ? ((dst == ctx_Wt) ? 2304 : ((dst == out_Wt) ? 768 : 256))
                                 : 768;
        const int ct = C >> 5;
        const int r0 = (bid / ct) * 32, c0 = (bid % ct) * 32;
        const int tx = tid & 31, ty = tid >> 5;
#pragma unroll
        for (int i = 0; i < 32; i += 8)
            smem[(ty + i) * 33 + tx] = src[(size_t)(r0 + ty + i) * C + c0 + tx];
        __syncthreads();
#pragma unroll
        for (int i = 0; i < 32; i += 8)
            dst[(size_t)(c0 + ty + i) * R + r0 + tx] = f2bf(smem[tx * 33 + ty + i]);
    } else if (bid < 4672) {
        const int l = bid - 4416;
        if (l >= LL) {
            for (int j = 0; j < 3; ++j) clipb[(size_t)l * DD + tid + j * 256] = 0;
            return;
        }
        float t[3]; float q = 0.f;
#pragma unroll
        for (int j = 0; j < 3; ++j) {
            t[j] = pe[(size_t)l * DD + tid + j * 256];
            q = fmaf(t[j], t[j], q);
        }
        q = breduce_sum<256>(q, smem);
        float inv = 1.f / fmaxf(sqrtf(q), 1e-12f);
#pragma unroll
        for (int j = 0; j < 3; ++j)
            clipb[(size_t)l * DD + tid + j * 256] = f2bf(t[j] * inv);
    } else {
        const int ebid = bid - 4672;
        if (ebid == 0) {
            for (int r = tid; r < MROWS; r += 256) {
                int w = wpos[r];
                cpos[r] = w < 0 ? 0 : (w > LL - 1 ? LL - 1 : w);
            }
            if (tid < 256) zbias[tid] = 0.f;
        }
        const int lane = tid & 63;
        const int wid = ebid * 4 + (tid >> 6);       // 0..8191
        const int NCHUNK = (TEXT_F4 + Q_F4) / 512;   // 18048
        for (int c = wid; c < NCHUNK; c += 8192) {
            const int base = c * 512;
            if (base < TEXT_F4) {
                const float4* sp = (const float4*)text;
                uint2* op = (uint2*)textb;
                float4 v[8];
#pragma unroll
                for (int j = 0; j < 8; ++j)
                    v[j] = sp[(size_t)base + j * 64 + lane];
#pragma unroll
                for (int j = 0; j < 8; ++j) {
                    uint2 o;
                    o.x = (u32)f2bf(v[j].x) | ((u32)f2bf(v[j].y) << 16);
                    o.y = (u32)f2bf(v[j].z) | ((u32)f2bf(v[j].w) << 16);
                    op[(size_t)base + j * 64 + lane] = o;
                }
            } else {
                const int qb4 = base - TEXT_F4;
                const float4* sp = (const float4*)wf;
                uint2* op = (uint2*)qb;
                float4 v[8]; float vfm[8];
#pragma unroll
                for (int j = 0; j < 8; ++j)
                    v[j] = sp[(size_t)qb4 + j * 64 + lane];
#pragma unroll
                for (int j = 0; j < 8; ++j)
                    vfm[j] = (wpos[(qb4 + j * 64 + lane) / 192] != -1) ? 1.f : 0.f;
#pragma unroll
                for (int j = 0; j < 8; ++j) {
                    uint2 o;
                    o.x = (u32)f2bf(v[j].x * vfm[j]) | ((u32)f2bf(v[j].y * vfm[j]) << 16);
                    o.y = (u32)f2bf(v[j].z * vfm[j]) | ((u32)f2bf(v[j].w * vfm[j]) << 16);
                    op[(size_t)qb4 + j * 64 + lane] = o;
                }
            }
        }
    }
}

// ---------------------------------------------------------------------------
// GEMM tile body (device fn), BK=64: 128x128 tile, 4 waves, 32 MFMA/K-step.
// Swizzle involution for 128B rows (proven r8-r12).
// ---------------------------------------------------------------------------
template<int GATHER, int CBF16, int MASK>
__device__ __forceinline__ void gemm_tile(
    const int m0, const int n0,
    const u16* __restrict__ A,
    const u16* __restrict__ TXT,
    const int* __restrict__ cpos,
    const u16* __restrict__ Bt,
    const float* __restrict__ bias,
    void* __restrict__ Cout, int ldc, int K,
    const int* __restrict__ wpos,
    u16* Alds, u16* Blds) {
    const int tid = threadIdx.x;
    const int l = tid & 63, wv = tid >> 6;

    const int rw = wv * 8 + (l >> 3);
    const int ce = ((l & 7) ^ (l >> 3)) << 3;
    u16* Ad0 = Alds + wv * 512;
    u16* Bd0 = Blds + wv * 512;

    const int wm = (wv >> 1) * 64, wn = (wv & 1) * 64;
    const int la = l & 15, lg = l >> 4;

    int aoff[4], boff[4];
#pragma unroll
    for (int m = 0; m < 4; ++m) {
        int ra = wm + m * 16 + la;
        aoff[m] = ra * 64 + (((lg ^ (la & 7)) << 3));
        int rb = wn + m * 16 + la;
        boff[m] = rb * 64 + (((lg ^ (la & 7)) << 3));
    }

    const u16* pb[4];
#pragma unroll
    for (int i = 0; i < 4; ++i)
        pb[i] = Bt + (size_t)(n0 + rw + i * 32) * K + ce;

    f32x4 acc[4][4] = {};

    auto do_step = [&](const u16* a0, const u16* a1, const u16* a2, const u16* a3,
                       const u16* b0, const u16* b1, const u16* b2, const u16* b3) {
        gload16(a0, Ad0);
        gload16(a1, Ad0 + 2048);
        gload16(a2, Ad0 + 4096);
        gload16(a3, Ad0 + 6144);
        gload16(b0, Bd0);
        gload16(b1, Bd0 + 2048);
        gload16(b2, Bd0 + 4096);
        gload16(b3, Bd0 + 6144);
        __syncthreads();
#pragma unroll
        for (int kk = 0; kk < 2; ++kk) {
            const int kx = kk << 5;
            s16x8 af[4], bf[4];
#pragma unroll
            for (int m = 0; m < 4; ++m) af[m] = *(const s16x8*)(Alds + (aoff[m] ^ kx));
#pragma unroll
            for (int n = 0; n < 4; ++n) bf[n] = *(const s16x8*)(Blds + (boff[n] ^ kx));
#pragma unroll
            for (int m = 0; m < 4; ++m)
#pragma unroll
                for (int n = 0; n < 4; ++n)
                    acc[m][n] = __builtin_amdgcn_mfma_f32_16x16x32_bf16(
                        af[m], bf[n], acc[m][n], 0, 0, 0);
        }
        __syncthreads();
    };

    if constexpr (GATHER) {
        int gb[4], gc[4];
#pragma unroll
        for (int i = 0; i < 4; ++i) {
            int g = m0 + rw + i * 32;
            gb[i] = g >> 7;
            gc[i] = cpos[g];
        }
#pragma unroll 1
        for (int w = 0; w < 3; ++w) {
            const u16* pa[4];
#pragma unroll
            for (int i = 0; i < 4; ++i) {
                int p = gc[i] + w - 1;
                p = p < 0 ? 0 : (p > LL - 1 ? LL - 1 : p);
                pa[i] = TXT + ((size_t)(gb[i] * LL + p)) * DD + ce;
            }
            const u16* b0 = pb[0] + w * DD; const u16* b1 = pb[1] + w * DD;
            const u16* b2 = pb[2] + w * DD; const u16* b3 = pb[3] + w * DD;
#pragma unroll 1
            for (int kt = 0; kt < 12; ++kt)
                do_step(pa[0] + kt * 64, pa[1] + kt * 64, pa[2] + kt * 64, pa[3] + kt * 64,
                        b0 + kt * 64, b1 + kt * 64, b2 + kt * 64, b3 + kt * 64);
        }
    } else {
        const u16* pa[4];
#pragma unroll
        for (int i = 0; i < 4; ++i)
            pa[i] = A + (size_t)(m0 + rw + i * 32) * K + ce;
        const int nk = K >> 6;
#pragma unroll 1
        for (int kt = 0; kt < nk; ++kt)
            do_step(pa[0] + (kt << 6), pa[1] + (kt << 6), pa[2] + (kt << 6), pa[3] + (kt << 6),
                    pb[0] + (kt << 6), pb[1] + (kt << 6), pb[2] + (kt << 6), pb[3] + (kt << 6));
    }

#pragma unroll
    for (int m = 0; m < 4; ++m) {
        const int rb = m0 + wm + m * 16 + lg * 4;
        float vf[4];
        if constexpr (MASK) {
#pragma unroll
            for (int r = 0; r < 4; ++r) vf[r] = (wpos[rb + r] != -1) ? 1.f : 0.f;
        }
#pragma unroll
        for (int n = 0; n < 4; ++n) {
            const int col = n0 + wn + n * 16 + la;
            const float bv = bias[col];
#pragma unroll
            for (int r = 0; r < 4; ++r) {
                float o = acc[m][n][r] + bv;
                if constexpr (MASK) o *= vf[r];
                if constexpr (CBF16)
                    ((u16*)Cout)[(size_t)(rb + r) * ldc + col] = f2bf(o);
                else
                    ((float*)Cout)[(size_t)(rb + r) * ldc + col] = o;
            }
        }
    }
}

// ---------------------------------------------------------------------------
// Standalone GEMM kernel (XCD swizzle inside); used for kv, out, r1, r2
// ---------------------------------------------------------------------------
template<int GATHER, int CBF16, int MASK>
__global__ __launch_bounds__(256)
void gemm_bt(const u16* __restrict__ A,
             const u16* __restrict__ TXT,
             const int* __restrict__ cpos,
             const u16* __restrict__ Bt,
             const float* __restrict__ bias,
             void* __restrict__ Cout, int ldc, int K,
             const int* __restrict__ wpos) {
    __shared__ __align__(16) u16 Alds[128 * 64];
    __shared__ __align__(16) u16 Blds[128 * 64];
    const int gx  = gridDim.x;
    const int hw  = blockIdx.y * gx + blockIdx.x;
    const int nwg = gx * gridDim.y;
    const int cpx = nwg >> 3;
    const int lin = (hw & 7) * cpx + (hw >> 3);
    const int m0 = (lin / gx) * 128, n0 = (lin % gx) * 128;
    gemm_tile<GATHER, CBF16, MASK>(m0, n0, A, TXT, cpos, Bt, bias,
                                   Cout, ldc, K, wpos, Alds, Blds);
}

// ---------------------------------------------------------------------------
// MERGED: ctx GEMM (blocks 0..767) + qp GEMM (blocks 768..1535).
// Independent ops share one dispatch; XCD swizzle per sub-grid (nwg=768, %8==0).
// ---------------------------------------------------------------------------
__global__ __launch_bounds__(256)
void gemm_ctx_qp_kernel(const u16* __restrict__ textb, const int* __restrict__ cpos,
                        const u16* __restrict__ ctx_Wt, const float* __restrict__ ctx_b,
                        u16* __restrict__ ctxa,
                        const u16* __restrict__ qb, const u16* __restrict__ in_Wt,
                        const float* __restrict__ in_b, u16* __restrict__ qpb,
                        const int* __restrict__ wpos) {
    __shared__ __align__(16) u16 Alds[128 * 64];
    __shared__ __align__(16) u16 Blds[128 * 64];
    const int bid = blockIdx.x;
    if (bid < 768) {
        const int lin = (bid & 7) * 96 + (bid >> 3);
        const int m0 = (lin / 6) * 128, n0 = (lin % 6) * 128;
        gemm_tile<1, 1, 1>(m0, n0, nullptr, textb, cpos, ctx_Wt, ctx_b,
                           ctxa, DD, 3 * DD, wpos, Alds, Blds);
    } else {
        const int b2 = bid - 768;
        const int lin = (b2 & 7) * 96 + (b2 >> 3);
        const int m0 = (lin / 6) * 128, n0 = (lin % 6) * 128;
        gemm_tile<0, 1, 0>(m0, n0, qb, nullptr, nullptr, in_Wt, in_b,
                           qpb, DD, DD, nullptr, Alds, Blds);
    }
}

// ---------------------------------------------------------------------------
// rel Gram tile at 256 threads (4 waves x 2 row-groups), for co-dispatch
// ---------------------------------------------------------------------------
__device__ __forceinline__ void rel_tile(int blk, const u16* __restrict__ rnb,
                                         const int* __restrict__ wpos,
                                         float* __restrict__ rel_part,
                                         float* __restrict__ vm2_part,
                                         u16* T /* >= 8KB + 1KB red */) {
    float* red = (float*)(T + 4096);   // bytes [8192, 9216)
    const int b = blk >> 1, jh = blk & 1;
    const int tid = threadIdx.x;
    const int l = tid & 63, wv = tid >> 6;   // wv 0..3
    const int la = l & 15, lg = l >> 4;

    // staging: two 4KB issues per K-step
    const int f0 = wv * 1024 + l * 16;
    const int f1 = f0 + 4096;
    const int rA0 = f0 >> 6, rA1 = f1 >> 6;
    const int ce0 = ((f0 & 63) ^ (((rA0 >> 1) & 3) << 4)) >> 1;
    const int ce1 = ((f1 & 63) ^ (((rA1 >> 1) & 3) << 4)) >> 1;
    const u16* src0 = rnb + ((size_t)(b * NN + rA0)) * DD + ce0;
    const u16* src1 = rnb + ((size_t)(b * NN + rA1)) * DD + ce1;
    u16* dst0 = T + wv * 512;
    u16* dst1 = T + 2048 + wv * 512;

    int aoff[2];
#pragma unroll
    for (int g = 0; g < 2; ++g) {
        int ra = wv * 32 + g * 16 + la;
        aoff[g] = ra * 32 + ((lg * 8) ^ (((ra >> 1) & 3) << 3));
    }
    int boff[4];
#pragma unroll
    for (int nf = 0; nf < 4; ++nf) {
        int rb = jh * 64 + nf * 16 + la;
        boff[nf] = rb * 32 + ((lg * 8) ^ (((rb >> 1) & 3) << 3));
    }

    f32x4 acc[2][4] = {};
    for (int kt = 0; kt < 24; ++kt) {
        gload16(src0 + kt * 32, dst0);
        gload16(src1 + kt * 32, dst1);
        __syncthreads();
        s16x8 a[2], bf_[4];
#pragma unroll
        for (int g = 0; g < 2; ++g) a[g] = *(const s16x8*)(T + aoff[g]);
#pragma unroll
        for (int nf = 0; nf < 4; ++nf) bf_[nf] = *(const s16x8*)(T + boff[nf]);
#pragma unroll
        for (int g = 0; g < 2; ++g)
#pragma unroll
            for (int nf = 0; nf < 4; ++nf)
                acc[g][nf] = __builtin_amdgcn_mfma_f32_16x16x32_bf16(
                    a[g], bf_[nf], acc[g][nf], 0, 0, 0);
        __syncthreads();
    }

    float csum = 0.f, msum = 0.f;
#pragma unroll
    for (int g = 0; g < 2; ++g) {
        float wif[4], vi[4];
#pragma unroll
        for (int r = 0; r < 4; ++r) {
            int wi = wpos[b * NN + wv * 32 + g * 16 + lg * 4 + r];
            vi[r] = (wi != -1) ? 1.f : 0.f;
            wif[r] = (float)(wi < 0 ? 0 : (wi > LL - 1 ? LL - 1 : wi));
        }
#pragma unroll
        for (int nf = 0; nf < 4; ++nf) {
            int wj = wpos[b * NN + jh * 64 + nf * 16 + la];
            float vj = (wj != -1) ? 1.f : 0.f;
            float wjf = (float)(wj < 0 ? 0 : (wj > LL - 1 ? LL - 1 : wj));
#pragma unroll
            for (int r = 0; r < 4; ++r) {
                float sim = (acc[g][nf][r] + 1.f) * 0.5f;
                float ts  = 1.f - fabsf(wif[r] - wjf) * (1.f / (float)LL);
                float m2  = vi[r] * vj;
                float df  = m2 * (sim - ts);
                csum += df * df;
                msum += m2;
            }
        }
    }
    csum = breduce_sum<256>(csum, red);
    msum = breduce_sum<256>(msum, red);
    if (tid == 0) { rel_part[blk] = csum; vm2_part[blk] = msum; }
}

// ---------------------------------------------------------------------------
// MERGED: logits GEMM (blocks 0..255) + rel Gram (blocks 256..511)
// ---------------------------------------------------------------------------
__global__ __launch_bounds__(256)
void logits_rel_kernel(const u16* __restrict__ rnb, const u16* __restrict__ clipb,
                       const float* __restrict__ zbias, float* __restrict__ logits,
                       const int* __restrict__ wpos,
                       float* __restrict__ relp, float* __restrict__ vmp) {
    __shared__ __align__(16) u16 pool[2 * 128 * 64];   // 32 KB
    const int bid = blockIdx.x;
    if (bid < 256) {
        const int lin = (bid & 7) * 32 + (bid >> 3);
        const int m0 = (lin >> 1) * 128, n0 = (lin & 1) * 128;
        gemm_tile<0, 0, 0>(m0, n0, rnb, nullptr, nullptr, clipb, zbias,
                           logits, 256, DD, nullptr, pool, pool + 128 * 64);
    } else {
        rel_tile(bid - 256, rnb, wpos, relp, vmp, pool);
    }
}

// ---------------------------------------------------------------------------
// MFMA attention (unchanged)
// ---------------------------------------------------------------------------
__global__ __launch_bounds__(512)
void attn_mfma_kernel(const u16* __restrict__ qp, const u16* __restrict__ kvb,
                      u16* __restrict__ ao) {
    __shared__ __align__(16) u16 K_lds[128 * 96];
    __shared__ __align__(16) u16 Vt_lds[96 * 128];
    __shared__ __align__(16) u16 P_lds[128 * 128];
    const int bh = blockIdx.x;
    const int b = bh >> 3, h = bh & 7;
    const int tid = threadIdx.x;
    const int l = tid & 63, wv = tid >> 6;
    const int la = l & 15, lg = l >> 4;
    const float scale = 0.10206207261596575f;

    const size_t qbase  = ((size_t)b * NN) * DD + h * HDh;
    const size_t kvbase = ((size_t)b * NN) * KVLD + h * HDh;

#pragma unroll
    for (int i = 0; i < 3; ++i) {
        int f = i * 8192 + wv * 1024 + l * 16;
        int row = f / 192;
        int inner = f - row * 192;
        gload16((const char*)(kvb + kvbase + (size_t)row * KVLD) + inner,
                (char*)K_lds + f);
    }

    uint4 vchunk[3]; int vkey[3], vd0[3];
#pragma unroll
    for (int i = 0; i < 3; ++i) {
        int c = tid + i * 512;
        int key = c / 12, dc = c - key * 12;
        vkey[i] = key; vd0[i] = dc * 8;
        vchunk[i] = *(const uint4*)(kvb + kvbase + (size_t)key * KVLD + DD + dc * 8);
    }

    const int q0 = wv * 16;
    s16x8 qf[3];
#pragma unroll
    for (int kt = 0; kt < 3; ++kt)
        qf[kt] = *(const s16x8*)(qp + qbase + (size_t)(q0 + la) * DD + kt * 32 + lg * 8);

#pragma unroll
    for (int i = 0; i < 3; ++i) {
        const u16* e = (const u16*)&vchunk[i];
#pragma unroll
        for (int j = 0; j < 8; ++j) {
            int d = vd0[i] + j;
            int byte = ((d * 128 + vkey[i]) * 2) ^ ((d & 7) << 4);
            *(u16*)((char*)Vt_lds + byte) = e[j];
        }
    }
    __syncthreads();

    f32x4 sacc[8] = {};
#pragma unroll
    for (int kt = 0; kt < 3; ++kt) {
#pragma unroll
        for (int nf = 0; nf < 8; ++nf) {
            s16x8 bfr = *(const s16x8*)(K_lds + (nf * 16 + la) * 96 + kt * 32 + lg * 8);
            sacc[nf] = __builtin_amdgcn_mfma_f32_16x16x32_bf16(qf[kt], bfr, sacc[nf], 0, 0, 0);
        }
    }

#pragma unroll
    for (int r = 0; r < 4; ++r) {
        float m = -1e30f;
#pragma unroll
        for (int nf = 0; nf < 8; ++nf) m = fmaxf(m, sacc[nf][r]);
#pragma unroll
        for (int o = 8; o > 0; o >>= 1) m = fmaxf(m, __shfl_xor(m, o, 64));
        m *= scale;
        float p[8]; float s = 0.f;
#pragma unroll
        for (int nf = 0; nf < 8; ++nf) { p[nf] = expf(sacc[nf][r] * scale - m); s += p[nf]; }
#pragma unroll
        for (int o = 8; o > 0; o >>= 1) s += __shfl_xor(s, o, 64);
        const float inv = 1.f / s;
        const int q = q0 + lg * 4 + r;
#pragma unroll
        for (int nf = 0; nf < 8; ++nf) {
            int byte = ((q * 128 + nf * 16 + la) * 2) ^ ((q & 7) << 4);
            *(u16*)((char*)P_lds + byte) = f2bf(p[nf] * inv);
        }
    }
    __syncthreads();

    f32x4 oacc[6] = {};
#pragma unroll
    for (int kk = 0; kk < 4; ++kk) {
        const int qrow = q0 + la;
        int abyte = ((qrow * 128 + kk * 32 + lg * 8) * 2) ^ ((qrow & 7) << 4);
        s16x8 af = *(const s16x8*)((char*)P_lds + abyte);
#pragma unroll
        for (int nf = 0; nf < 6; ++nf) {
            const int d = nf * 16 + la;
            int bbyte = ((d * 128 + kk * 32 + lg * 8) * 2) ^ ((d & 7) << 4);
            s16x8 bfr = *(const s16x8*)((char*)Vt_lds + bbyte);
            oacc[nf] = __builtin_amdgcn_mfma_f32_16x16x32_bf16(af, bfr, oacc[nf], 0, 0, 0);
        }
    }

#pragma unroll
    for (int nf = 0; nf < 6; ++nf) {
#pragma unroll
        for (int r = 0; r < 4; ++r) {
            const int q = q0 + lg * 4 + r;
            ao[qbase + (size_t)q * DD + nf * 16 + la] = f2bf(oacc[nf][r]);
        }
    }
}

// ---------------------------------------------------------------------------
// x = layernorm(q + attn_out)*vf -> bf16
// ---------------------------------------------------------------------------
__global__ __launch_bounds__(256)
void ln768_kernel(const u16* __restrict__ qb, const u16* __restrict__ at,
                  const int* __restrict__ wpos, const float* __restrict__ g,
                  const float* __restrict__ bta, u16* __restrict__ xout) {
    __shared__ float red[256];
    const int r = blockIdx.x, tid = threadIdx.x;
    const float vf = (wpos[r] != -1) ? 1.f : 0.f;
    float t[3]; float s = 0.f, q = 0.f;
#pragma unroll
    for (int j = 0; j < 3; ++j) {
        int d = tid + j * 256;
        t[j] = bf2f(qb[(size_t)r * DD + d]) + bf2f(at[(size_t)r * DD + d]);
        s += t[j];
        q = fmaf(t[j], t[j], q);
    }
    s = breduce_sum<256>(s, red);
    q = breduce_sum<256>(q, red);
    float mean = s * (1.f / DD);
    float var  = q * (1.f / DD) - mean * mean;
    float inv  = 1.f / sqrtf(var + 1e-5f);
#pragma unroll
    for (int j = 0; j < 3; ++j) {
        int d = tid + j * 256;
        xout[(size_t)r * DD + d] = f2bf(((t[j] - mean) * inv * g[d] + bta[d]) * vf);
    }
}

// ---------------------------------------------------------------------------
// h = layernorm(gelu(g1)) -> bf16
// ---------------------------------------------------------------------------
__global__ __launch_bounds__(256)
void ln256_gelu_kernel(const u16* __restrict__ g1, const float* __restrict__ lg,
                       const float* __restrict__ lb, u16* __restrict__ hout) {
    __shared__ float red[256];
    const int r = blockIdx.x, tid = threadIdx.x;
    float v  = bf2f(g1[(size_t)r * HIDN + tid]);
    float ge = 0.5f * v * (1.f + erff(v * 0.7071067811865475f));
    float s = breduce_sum<256>(ge, red);
    float q = breduce_sum<256>(ge * ge, red);
    float mean = s * (1.f / HIDN);
    float var  = q * (1.f / HIDN) - mean * mean;
    float inv  = 1.f / sqrtf(var + 1e-5f);
    hout[(size_t)r * HIDN + tid] = f2bf((ge - mean) * inv * lg[tid] + lb[tid]);
}

// ---------------------------------------------------------------------------
// MERGED: norm_rnb (blocks 0..16383) + emb full write (blocks 16384..48127)
// Both depend only on ropeb.
// ---------------------------------------------------------------------------
__global__ __launch_bounds__(256)
void norm_emb_kernel(const u16* __restrict__ ropeb, const float* __restrict__ pe,
                     const int* __restrict__ wpos, u16* __restrict__ rnb,
                     float* __restrict__ emb) {
    __shared__ float red[256];
    const int bid = blockIdx.x;
    const int tid = threadIdx.x;
    if (bid < MROWS) {
        const int r = bid;
        float t[3]; float q = 0.f;
#pragma unroll
        for (int j = 0; j < 3; ++j) {
            t[j] = bf2f(ropeb[(size_t)r * DD + tid + j * 256]);
            q = fmaf(t[j], t[j], q);
        }
        q = breduce_sum<256>(q, red);
        float inv = 1.f / fmaxf(sqrtf(q), 1e-12f);
#pragma unroll
        for (int j = 0; j < 3; ++j)
            rnb[(size_t)r * DD + tid + j * 256] = f2bf(t[j] * inv);
    } else {
        const int bl = bid - MROWS;
        const int b = bl / LL, l = bl - b * LL;
        const int* wp = wpos + b * NN;
        int lo = 0, hi = NN - 1, found = -1;
        while (lo <= hi) {
            int mid = (lo + hi) >> 1;
            int v = wp[mid];
            if (v == l) { found = mid; break; }
            if (v < l) lo = mid + 1; else hi = mid - 1;
        }
        float* dst = emb + (size_t)bl * DD;
        if (found >= 0) {
            const u16* rr = ropeb + (size_t)(b * NN + found) * DD;
#pragma unroll
            for (int j = 0; j < 3; ++j) {
                int d = tid + j * 256;
                dst[d] = 0.8f * pe[(size_t)l * DD + d] + 0.2f * bf2f(rr[d]);
            }
        } else {
#pragma unroll
            for (int j = 0; j < 3; ++j)
                dst[tid + j * 256] = 0.f;
        }
    }
}

// ---------------------------------------------------------------------------
// KL from precomputed logits. One WAVE per row, 4 rows/block.
// ---------------------------------------------------------------------------
__global__ __launch_bounds__(256)
void kl_lite_kernel(const float* __restrict__ logits, const int* __restrict__ wpos,
                    const float* __restrict__ pos_temp, float* __restrict__ klp) {
    const int row = blockIdx.x * 4 + (threadIdx.x >> 6);
    const int l = threadIdx.x & 63;
    const float invt = 1.f / fmaxf(pos_temp[0], 0.001f);
    const float* lrow = logits + (size_t)row * 256;

    float lg[4];
#pragma unroll
    for (int q = 0; q < 4; ++q) {
        int c = l + q * 64;
        lg[q] = (c < LL) ? lrow[c] * invt : -1e30f;
    }
    float m = fmaxf(fmaxf(lg[0], lg[1]), fmaxf(lg[2], lg[3]));
#pragma unroll
    for (int o = 32; o > 0; o >>= 1) m = fmaxf(m, __shfl_xor(m, o, 64));

    float S = 0.f;
#pragma unroll
    for (int q = 0; q < 4; ++q) S += expf(lg[q] - m);
#pragma unroll
    for (int o = 32; o > 0; o >>= 1) S += __shfl_xor(S, o, 64);
    const float logZ = m + logf(S);

    const int wr = wpos[row];
    const bool valid = (wr != -1);
    const int wp = wr < 0 ? 0 : (wr > LL - 1 ? LL - 1 : wr);

    float targ[4]; float tsum = 0.f;
#pragma unroll
    for (int q = 0; q < 4; ++q) {
        int c = l + q * 64;
        float dl = (float)c - (float)wp;
        targ[q] = (c < LL) ? expf(-dl * dl * 0.125f) : 0.f;
        tsum += targ[q];
    }
#pragma unroll
    for (int o = 32; o > 0; o >>= 1) tsum += __shfl_xor(tsum, o, 64);
    const float tden = 1.f / (tsum + 1e-12f);

    float c_ = 0.f;
#pragma unroll
    for (int q = 0; q < 4; ++q) {
        float tn = targ[q] * tden;
        if (valid && tn > 0.f) c_ += tn * (logf(tn) - (lg[q] - logZ));
    }
#pragma unroll
    for (int o = 32; o > 0; o >>= 1) c_ += __shfl_xor(c_, o, 64);
    if (l == 0) klp[row] = c_;
}

// ---------------------------------------------------------------------------
// Final deterministic fp64 reduction
// ---------------------------------------------------------------------------
__global__ __launch_bounds__(256)
void final_kernel(const float* __restrict__ klp, const float* __restrict__ relp,
                  const float* __restrict__ vmp, const int* __restrict__ wpos,
                  float* __restrict__ outs) {
    __shared__ double rd[256];
    const int tid = threadIdx.x;
    double kl = 0.0, rel = 0.0, vm = 0.0, nv = 0.0;
    for (int r = tid; r < MROWS; r += 256) {
        kl += (double)klp[r];
        nv += (wpos[r] != -1) ? 1.0 : 0.0;
    }
    if (tid < 256) {
        rel += (double)relp[tid];
        vm  += (double)vmp[tid];
    }
    kl  = breduce_sum_d256(kl, rd);
    rel = breduce_sum_d256(rel, rd);
    vm  = breduce_sum_d256(vm, rd);
    nv  = breduce_sum_d256(nv, rd);
    if (tid == 0) {
        float klf  = (float)(kl / (nv + 1e-12));
        float relf = (float)(rel / (vm + 1e-12));
        outs[0] = klf + 0.5f * relf;
        outs[1] = klf;
        outs[2] = relf;
    }
}

// ---------------------------------------------------------------------------
extern "C" void kernel_launch(void* const* d_in, const int* in_sizes, int n_in,
                              void* d_out, int out_size, void* d_ws, size_t ws_size,
                              hipStream_t stream) {
    (void)in_sizes; (void)n_in; (void)ws_size; (void)out_size;

    const float* word_feat = (const float*)d_in[0];
    const float* text      = (const float*)d_in[1];
    const int*   wpos      = (const int*)d_in[2];
    const float* ctx_W     = (const float*)d_in[3];
    const float* ctx_b     = (const float*)d_in[4];
    const float* in_W      = (const float*)d_in[5];
    const float* in_b      = (const float*)d_in[6];
    const float* out_W     = (const float*)d_in[7];
    const float* out_b     = (const float*)d_in[8];
    const float* cn_g      = (const float*)d_in[9];
    const float* cn_b      = (const float*)d_in[10];
    const float* r1_W      = (const float*)d_in[11];
    const float* r1_b      = (const float*)d_in[12];
    const float* ln_g      = (const float*)d_in[13];
    const float* ln_b      = (const float*)d_in[14];
    const float* r2_W      = (const float*)d_in[15];
    const float* r2_b      = (const float*)d_in[16];
    const float* pos_emb   = (const float*)d_in[17];
    const float* pos_temp  = (const float*)d_in[18];

    char* W = (char*)d_ws;
    // --- weight/partials area [0, 12MB) ---
    u16*   ctx_Wt = (u16*)(W);
    u16*   in_Wt  = ctx_Wt + (size_t)768 * 2304;
    u16*   out_Wt = in_Wt  + (size_t)2304 * 768;
    u16*   r1_Wt  = out_Wt + (size_t)768 * 768;
    u16*   r2_Wt  = r1_Wt  + (size_t)256 * 768;
    u16*   clipb  = r2_Wt + (size_t)768 * 256;          // [256][768] bf16
    int*   cposb  = (int*)(clipb + (size_t)256 * DD);
    float* klp    = (float*)(cposb + MROWS);
    float* relp   = klp + MROWS;
    float* vmp    = relp + 256;
    float* zbias  = vmp + 256;                           // 256 zero floats
    // --- big regions (lifetimes audited) ---
    u16*   textb  = (u16*)(W + (size_t)12 * MB_);   // 12-58.5, dead after ctx GEMM
    u16*   atoutb = textb;                           // reuse 12-36
    float* logits = (float*)(W + (size_t)12 * MB_);  // reuse 12-28
    u16*   xb     = (u16*)(W + (size_t)36 * MB_);   // 36-60
    u16*   qb     = (u16*)(W + (size_t)60 * MB_);   // 60-84
    u16*   ctxa   = (u16*)(W + (size_t)86 * MB_);   // 86-110
    u16*   aob    = ctxa;
    u16*   rnb    = ctxa;
    u16*   qpb    = (u16*)(W + (size_t)112 * MB_);  // 112-136
    u16*   g1b    = (u16*)(W + (size_t)112 * MB_);  // reuse 112-120
    u16*   hb     = (u16*)(W + (size_t)128 * MB_);  // 128-136.4
    u16*   kvb    = (u16*)(W + (size_t)138 * MB_);  // 138-186
    u16*   ropeb  = kvb;                             // reuse 138-162

    dim3 blk(256);

    // 1. prep: transposes + clip_n + elementwise + cpos + zbias
    prep_all_kernel<<<dim3(4416 + 256 + 2048), blk, 0, stream>>>(
        ctx_W, ctx_Wt, in_W, in_Wt, out_W, out_Wt, r1_W, r1_Wt, r2_W, r2_Wt,
        text, textb, word_feat, qb, wpos, cposb, pos_emb, clipb, zbias);

    dim3 g768(6, 128);
    dim3 g1536(12, 128);

    // 2. MERGED ctx GEMM + qp GEMM (independent)
    gemm_ctx_qp_kernel<<<dim3(1536), blk, 0, stream>>>(
        textb, cposb, ctx_Wt, ctx_b, ctxa, qb, in_Wt, in_b, qpb, wpos);
    // 3. fused kp|vp
    gemm_bt<0, 1, 0><<<g1536, blk, 0, stream>>>(
        ctxa, nullptr, nullptr, in_Wt + (size_t)768 * 768, in_b + DD, kvb, KVLD, DD, nullptr);
    // 4. MFMA attention -> ao (overwrites ctxa)
    attn_mfma_kernel<<<dim3(BB * HH), dim3(512), 0, stream>>>(qpb, kvb, aob);
    // 5. attn_out = ao @ out_W + out_b
    gemm_bt<0, 1, 0><<<g768, blk, 0, stream>>>(
        aob, nullptr, nullptr, out_Wt, out_b, atoutb, DD, DD, nullptr);
    // 6. x = LN(q + attn_out)*vf
    ln768_kernel<<<dim3(MROWS), blk, 0, stream>>>(qb, atoutb, wpos, cn_g, cn_b, xb);
    // 7. g1 = x @ r1_W + r1_b -> bf16
    gemm_bt<0, 1, 0><<<dim3(2, 128), blk, 0, stream>>>(
        xb, nullptr, nullptr, r1_Wt, r1_b, g1b, HIDN, DD, nullptr);
    // 8. h = LN(gelu(g1))
    ln256_gelu_kernel<<<dim3(MROWS), blk, 0, stream>>>(g1b, ln_g, ln_b, hb);
    // 9. rope = h @ r2_W + r2_b -> bf16
    gemm_bt<0, 1, 0><<<g768, blk, 0, stream>>>(
        hb, nullptr, nullptr, r2_Wt, r2_b, ropeb, DD, HIDN, nullptr);
    // 10. MERGED norm_rnb + emb full write (both read ropeb only)
    norm_emb_kernel<<<dim3(MROWS + BB * LL), blk, 0, stream>>>(
        ropeb, pos_emb, wpos, rnb, (float*)d_out);
    // 11. MERGED logits GEMM + rel Gram (both read rnb only)
    logits_rel_kernel<<<dim3(512), blk, 0, stream>>>(
        rnb, clipb, zbias, logits, wpos, relp, vmp);
    // 12. KL from logits
    kl_lite_kernel<<<dim3(MROWS / 4), blk, 0, stream>>>(logits, wpos, pos_temp, klp);
    // 13. scalars
    final_kernel<<<dim3(1), blk, 0, stream>>>(
        klp, relp, vmp, wpos, (float*)d_out + (size_t)BB * LL * DD);
}

// Round 14
// 400.677 us; speedup vs baseline: 1.1180x; 1.0809x over previous
//
#include <hip/hip_runtime.h>
#include <math.h>

// Problem constants
#define BB   128
#define NN   128
#define LL   248
#define DD   768
#define HH   8
#define HDh  96
#define HIDN 256
#define MROWS (BB*NN)   // 16384
#define MB_   (1u<<20)
#define KVLD 1536       // fused K|V row stride (elements)

typedef unsigned short u16;
typedef unsigned int   u32;
typedef __attribute__((ext_vector_type(8))) short s16x8;
typedef __attribute__((ext_vector_type(4))) float f32x4;

// ---------------------------------------------------------------------------
// helpers
// ---------------------------------------------------------------------------
__device__ __forceinline__ u16 f2bf(float x) {
    u32 u = __float_as_uint(x);
    u32 r = u + 0x7fffu + ((u >> 16) & 1u);
    return (u16)(r >> 16);
}
__device__ __forceinline__ float bf2f(u16 h) {
    return __uint_as_float(((u32)h) << 16);
}
__device__ __forceinline__ void gload16(const void* g, void* l) {
    __builtin_amdgcn_global_load_lds(
        (const __attribute__((address_space(1))) void*)g,
        (__attribute__((address_space(3))) void*)l, 16, 0, 0);
}

template<int NT>
__device__ __forceinline__ float breduce_sum(float v, float* red) {
    const int tid = threadIdx.x;
    red[tid] = v; __syncthreads();
#pragma unroll
    for (int o = NT / 2; o > 0; o >>= 1) {
        if (tid < o) red[tid] += red[tid + o];
        __syncthreads();
    }
    float r = red[0]; __syncthreads();
    return r;
}
__device__ __forceinline__ double breduce_sum_d256(double v, double* red) {
    const int tid = threadIdx.x;
    red[tid] = v; __syncthreads();
#pragma unroll
    for (int o = 128; o > 0; o >>= 1) {
        if (tid < o) red[tid] += red[tid + o];
        __syncthreads();
    }
    double r = red[0]; __syncthreads();
    return r;
}

// ---------------------------------------------------------------------------
// ONE prep dispatch (r12 structure)
// ---------------------------------------------------------------------------
#define TEXT_F4 (BB*LL*DD/4)     // 6094848  (multiple of 512)
#define Q_F4    (MROWS*(DD/4))   // 3145728  (multiple of 512)
__global__ __launch_bounds__(256)
void prep_all_kernel(const float* __restrict__ ctx_W, u16* __restrict__ ctx_Wt,
                     const float* __restrict__ in_W,  u16* __restrict__ in_Wt,
                     const float* __restrict__ out_W, u16* __restrict__ out_Wt,
                     const float* __restrict__ r1_W,  u16* __restrict__ r1_Wt,
                     const float* __restrict__ r2_W,  u16* __restrict__ r2_Wt,
                     const float* __restrict__ text,  u16* __restrict__ textb,
                     const float* __restrict__ wf,    u16* __restrict__ qb,
                     const int* __restrict__ wpos,    int* __restrict__ cpos,
                     const float* __restrict__ pe,    u16* __restrict__ clipb,
                     float* __restrict__ zbias) {
    __shared__ float smem[32 * 33];
    int bid = blockIdx.x;
    const int tid = threadIdx.x;

    if (bid < 4416) {
        const float* src; u16* dst; int C;
        if (bid < 1728)      { src = ctx_W; dst = ctx_Wt; C = 768;  }
        else if (bid < 3456) { src = in_W;  dst = in_Wt;  C = 2304; bid -= 1728; }
        else if (bid < 4032) { src = out_W; dst = out_Wt; C = 768;  bid -= 3456; }
        else if (bid < 4224) { src = r1_W;  dst = r1_Wt;  C = 256;  bid -= 4032; }
        else                 { src = r2_W;  dst = r2_Wt;  C = 768;  bid -= 4224; }
        const int R = (C == 768) ? ((dst == ctx_Wt) ? 2304 : ((dst == out_Wt) ? 768 : 256))
                                 : 768;
        const int ct = C >> 5;
        const int r0 = (bid / ct) * 32, c0 = (bid % ct) * 32;
        const int tx = tid & 31, ty = tid >> 5;
#pragma unroll
        for (int i = 0; i < 32; i += 8)
            smem[(ty + i) * 33 + tx] = src[(size_t)(r0 + ty + i) * C + c0 + tx];
        __syncthreads();
#pragma unroll
        for (int i = 0; i < 32; i += 8)
            dst[(size_t)(c0 + ty + i) * R + r0 + tx] = f2bf(smem[tx * 33 + ty + i]);
    } else if (bid < 4672) {
        const int l = bid - 4416;
        if (l >= LL) {
            for (int j = 0; j < 3; ++j) clipb[(size_t)l * DD + tid + j * 256] = 0;
            return;
        }
        float t[3]; float q = 0.f;
#pragma unroll
        for (int j = 0; j < 3; ++j) {
            t[j] = pe[(size_t)l * DD + tid + j * 256];
            q = fmaf(t[j], t[j], q);
        }
        q = breduce_sum<256>(q, smem);
        float inv = 1.f / fmaxf(sqrtf(q), 1e-12f);
#pragma unroll
        for (int j = 0; j < 3; ++j)
            clipb[(size_t)l * DD + tid + j * 256] = f2bf(t[j] * inv);
    } else {
        const int ebid = bid - 4672;
        if (ebid == 0) {
            for (int r = tid; r < MROWS; r += 256) {
                int w = wpos[r];
                cpos[r] = w < 0 ? 0 : (w > LL - 1 ? LL - 1 : w);
            }
            if (tid < 256) zbias[tid] = 0.f;
        }
        const int lane = tid & 63;
        const int wid = ebid * 4 + (tid >> 6);       // 0..8191
        const int NCHUNK = (TEXT_F4 + Q_F4) / 512;   // 18048
        for (int c = wid; c < NCHUNK; c += 8192) {
            const int base = c * 512;
            if (base < TEXT_F4) {
                const float4* sp = (const float4*)text;
                uint2* op = (uint2*)textb;
                float4 v[8];
#pragma unroll
                for (int j = 0; j < 8; ++j)
                    v[j] = sp[(size_t)base + j * 64 + lane];
#pragma unroll
                for (int j = 0; j < 8; ++j) {
                    uint2 o;
                    o.x = (u32)f2bf(v[j].x) | ((u32)f2bf(v[j].y) << 16);
                    o.y = (u32)f2bf(v[j].z) | ((u32)f2bf(v[j].w) << 16);
                    op[(size_t)base + j * 64 + lane] = o;
                }
            } else {
                const int qb4 = base - TEXT_F4;
                const float4* sp = (const float4*)wf;
                uint2* op = (uint2*)qb;
                float4 v[8]; float vfm[8];
#pragma unroll
                for (int j = 0; j < 8; ++j)
                    v[j] = sp[(size_t)qb4 + j * 64 + lane];
#pragma unroll
                for (int j = 0; j < 8; ++j)
                    vfm[j] = (wpos[(qb4 + j * 64 + lane) / 192] != -1) ? 1.f : 0.f;
#pragma unroll
                for (int j = 0; j < 8; ++j) {
                    uint2 o;
                    o.x = (u32)f2bf(v[j].x * vfm[j]) | ((u32)f2bf(v[j].y * vfm[j]) << 16);
                    o.y = (u32)f2bf(v[j].z * vfm[j]) | ((u32)f2bf(v[j].w * vfm[j]) << 16);
                    op[(size_t)qb4 + j * 64 + lane] = o;
                }
            }
        }
    }
}

// ---------------------------------------------------------------------------
// GEMM tile body, MIN-2-PHASE double-buffer:
// LDS = 2x(A 16KB + B 16KB) = 64 KB. Per K-step: issue 8 prefetch
// global_load_lds into the OTHER buffer, ds_read+32 MFMA on the current
// buffer, then ONE __syncthreads() (drains vmcnt -> next buffer ready).
// Load latency overlaps the MFMA phase. Swizzle involution unchanged.
// Alds/Blds each point to 2*8192 u16 (buffer stride 8192).
// ---------------------------------------------------------------------------
template<int GATHER, int CBF16, int MASK>
__device__ __forceinline__ void gemm_tile(
    const int m0, const int n0,
    const u16* __restrict__ A,
    const u16* __restrict__ TXT,
    const int* __restrict__ cpos,
    const u16* __restrict__ Bt,
    const float* __restrict__ bias,
    void* __restrict__ Cout, int ldc, int K,
    const int* __restrict__ wpos,
    u16* Alds, u16* Blds) {
    const int tid = threadIdx.x;
    const int l = tid & 63, wv = tid >> 6;

    const int rw = wv * 8 + (l >> 3);
    const int ce = ((l & 7) ^ (l >> 3)) << 3;

    const int wm = (wv >> 1) * 64, wn = (wv & 1) * 64;
    const int la = l & 15, lg = l >> 4;

    int aoff[4], boff[4];
#pragma unroll
    for (int m = 0; m < 4; ++m) {
        int ra = wm + m * 16 + la;
        aoff[m] = ra * 64 + (((lg ^ (la & 7)) << 3));
        int rb = wn + m * 16 + la;
        boff[m] = rb * 64 + (((lg ^ (la & 7)) << 3));
    }

    const u16* pb[4];
#pragma unroll
    for (int i = 0; i < 4; ++i)
        pb[i] = Bt + (size_t)(n0 + rw + i * 32) * K + ce;

    // A row-base pointers (GATHER: one per window slot, clamps hoisted)
    const u16* pa[4];
    const u16* paw0[4]; const u16* paw1[4]; const u16* paw2[4];
    if constexpr (GATHER) {
#pragma unroll
        for (int i = 0; i < 4; ++i) {
            int g = m0 + rw + i * 32;
            int gb = g >> 7, gc = cpos[g];
            int p0 = gc - 1; p0 = p0 < 0 ? 0 : p0;
            int p1 = gc;
            int p2 = gc + 1; p2 = p2 > LL - 1 ? LL - 1 : p2;
            paw0[i] = TXT + ((size_t)(gb * LL + p0)) * DD + ce;
            paw1[i] = TXT + ((size_t)(gb * LL + p1)) * DD + ce;
            paw2[i] = TXT + ((size_t)(gb * LL + p2)) * DD + ce;
        }
    } else {
#pragma unroll
        for (int i = 0; i < 4; ++i)
            pa[i] = A + (size_t)(m0 + rw + i * 32) * K + ce;
    }

    auto STAGE = [&](int buf, int kt) {
        u16* Ad = Alds + buf * 8192 + wv * 512;
        u16* Bd = Blds + buf * 8192 + wv * 512;
        if constexpr (GATHER) {
            const int w = (kt >= 24) ? 2 : ((kt >= 12) ? 1 : 0);
            const int kin = kt - w * 12;
#pragma unroll
            for (int i = 0; i < 4; ++i) {
                const u16* ai = (w == 0) ? paw0[i] : ((w == 1) ? paw1[i] : paw2[i]);
                gload16(ai + kin * 64, Ad + i * 2048);
            }
        } else {
#pragma unroll
            for (int i = 0; i < 4; ++i)
                gload16(pa[i] + kt * 64, Ad + i * 2048);
        }
#pragma unroll
        for (int i = 0; i < 4; ++i)
            gload16(pb[i] + kt * 64, Bd + i * 2048);
    };

    f32x4 acc[4][4] = {};
    const int nk = GATHER ? 36 : (K >> 6);

    STAGE(0, 0);
    __syncthreads();
#pragma unroll 1
    for (int kt = 0; kt < nk; ++kt) {
        const int cur = kt & 1;
        if (kt + 1 < nk) STAGE(cur ^ 1, kt + 1);
        const int cb = cur * 8192;
#pragma unroll
        for (int kk = 0; kk < 2; ++kk) {
            const int kx = kk << 5;
            s16x8 af[4], bf[4];
#pragma unroll
            for (int m = 0; m < 4; ++m) af[m] = *(const s16x8*)(Alds + cb + (aoff[m] ^ kx));
#pragma unroll
            for (int n = 0; n < 4; ++n) bf[n] = *(const s16x8*)(Blds + cb + (boff[n] ^ kx));
#pragma unroll
            for (int m = 0; m < 4; ++m)
#pragma unroll
                for (int n = 0; n < 4; ++n)
                    acc[m][n] = __builtin_amdgcn_mfma_f32_16x16x32_bf16(
                        af[m], bf[n], acc[m][n], 0, 0, 0);
        }
        __syncthreads();
    }

#pragma unroll
    for (int m = 0; m < 4; ++m) {
        const int rb = m0 + wm + m * 16 + lg * 4;
        float vf[4];
        if constexpr (MASK) {
#pragma unroll
            for (int r = 0; r < 4; ++r) vf[r] = (wpos[rb + r] != -1) ? 1.f : 0.f;
        }
#pragma unroll
        for (int n = 0; n < 4; ++n) {
            const int col = n0 + wn + n * 16 + la;
            const float bv = bias[col];
#pragma unroll
            for (int r = 0; r < 4; ++r) {
                float o = acc[m][n][r] + bv;
                if constexpr (MASK) o *= vf[r];
                if constexpr (CBF16)
                    ((u16*)Cout)[(size_t)(rb + r) * ldc + col] = f2bf(o);
                else
                    ((float*)Cout)[(size_t)(rb + r) * ldc + col] = o;
            }
        }
    }
}

// ---------------------------------------------------------------------------
// Standalone GEMM kernel (XCD swizzle inside); used for kv, out, r1, r2
// ---------------------------------------------------------------------------
template<int GATHER, int CBF16, int MASK>
__global__ __launch_bounds__(256)
void gemm_bt(const u16* __restrict__ A,
             const u16* __restrict__ TXT,
             const int* __restrict__ cpos,
             const u16* __restrict__ Bt,
             const float* __restrict__ bias,
             void* __restrict__ Cout, int ldc, int K,
             const int* __restrict__ wpos) {
    __shared__ __align__(16) u16 AB[4 * 128 * 64];   // 64 KB (2x dbuf A+B)
    const int gx  = gridDim.x;
    const int hw  = blockIdx.y * gx + blockIdx.x;
    const int nwg = gx * gridDim.y;
    const int cpx = nwg >> 3;
    const int lin = (hw & 7) * cpx + (hw >> 3);
    const int m0 = (lin / gx) * 128, n0 = (lin % gx) * 128;
    gemm_tile<GATHER, CBF16, MASK>(m0, n0, A, TXT, cpos, Bt, bias,
                                   Cout, ldc, K, wpos, AB, AB + 2 * 8192);
}

// ---------------------------------------------------------------------------
// MERGED: ctx GEMM (blocks 0..767) + qp GEMM (blocks 768..1535)
// ---------------------------------------------------------------------------
__global__ __launch_bounds__(256)
void gemm_ctx_qp_kernel(const u16* __restrict__ textb, const int* __restrict__ cpos,
                        const u16* __restrict__ ctx_Wt, const float* __restrict__ ctx_b,
                        u16* __restrict__ ctxa,
                        const u16* __restrict__ qb, const u16* __restrict__ in_Wt,
                        const float* __restrict__ in_b, u16* __restrict__ qpb,
                        const int* __restrict__ wpos) {
    __shared__ __align__(16) u16 AB[4 * 128 * 64];   // 64 KB
    const int bid = blockIdx.x;
    if (bid < 768) {
        const int lin = (bid & 7) * 96 + (bid >> 3);
        const int m0 = (lin / 6) * 128, n0 = (lin % 6) * 128;
        gemm_tile<1, 1, 1>(m0, n0, nullptr, textb, cpos, ctx_Wt, ctx_b,
                           ctxa, DD, 3 * DD, wpos, AB, AB + 2 * 8192);
    } else {
        const int b2 = bid - 768;
        const int lin = (b2 & 7) * 96 + (b2 >> 3);
        const int m0 = (lin / 6) * 128, n0 = (lin % 6) * 128;
        gemm_tile<0, 1, 0>(m0, n0, qb, nullptr, nullptr, in_Wt, in_b,
                           qpb, DD, DD, nullptr, AB, AB + 2 * 8192);
    }
}

// ---------------------------------------------------------------------------
// rel Gram tile at 256 threads (single-buffer; small L2-resident K)
// ---------------------------------------------------------------------------
__device__ __forceinline__ void rel_tile(int blk, const u16* __restrict__ rnb,
                                         const int* __restrict__ wpos,
                                         float* __restrict__ rel_part,
                                         float* __restrict__ vm2_part,
                                         u16* T /* >= 9.25KB */) {
    float* red = (float*)(T + 4096);   // bytes [8192, 9216)
    const int b = blk >> 1, jh = blk & 1;
    const int tid = threadIdx.x;
    const int l = tid & 63, wv = tid >> 6;
    const int la = l & 15, lg = l >> 4;

    const int f0 = wv * 1024 + l * 16;
    const int f1 = f0 + 4096;
    const int rA0 = f0 >> 6, rA1 = f1 >> 6;
    const int ce0 = ((f0 & 63) ^ (((rA0 >> 1) & 3) << 4)) >> 1;
    const int ce1 = ((f1 & 63) ^ (((rA1 >> 1) & 3) << 4)) >> 1;
    const u16* src0 = rnb + ((size_t)(b * NN + rA0)) * DD + ce0;
    const u16* src1 = rnb + ((size_t)(b * NN + rA1)) * DD + ce1;
    u16* dst0 = T + wv * 512;
    u16* dst1 = T + 2048 + wv * 512;

    int aoff[2];
#pragma unroll
    for (int g = 0; g < 2; ++g) {
        int ra = wv * 32 + g * 16 + la;
        aoff[g] = ra * 32 + ((lg * 8) ^ (((ra >> 1) & 3) << 3));
    }
    int boff[4];
#pragma unroll
    for (int nf = 0; nf < 4; ++nf) {
        int rb = jh * 64 + nf * 16 + la;
        boff[nf] = rb * 32 + ((lg * 8) ^ (((rb >> 1) & 3) << 3));
    }

    f32x4 acc[2][4] = {};
    for (int kt = 0; kt < 24; ++kt) {
        gload16(src0 + kt * 32, dst0);
        gload16(src1 + kt * 32, dst1);
        __syncthreads();
        s16x8 a[2], bf_[4];
#pragma unroll
        for (int g = 0; g < 2; ++g) a[g] = *(const s16x8*)(T + aoff[g]);
#pragma unroll
        for (int nf = 0; nf < 4; ++nf) bf_[nf] = *(const s16x8*)(T + boff[nf]);
#pragma unroll
        for (int g = 0; g < 2; ++g)
#pragma unroll
            for (int nf = 0; nf < 4; ++nf)
                acc[g][nf] = __builtin_amdgcn_mfma_f32_16x16x32_bf16(
                    a[g], bf_[nf], acc[g][nf], 0, 0, 0);
        __syncthreads();
    }

    float csum = 0.f, msum = 0.f;
#pragma unroll
    for (int g = 0; g < 2; ++g) {
        float wif[4], vi[4];
#pragma unroll
        for (int r = 0; r < 4; ++r) {
            int wi = wpos[b * NN + wv * 32 + g * 16 + lg * 4 + r];
            vi[r] = (wi != -1) ? 1.f : 0.f;
            wif[r] = (float)(wi < 0 ? 0 : (wi > LL - 1 ? LL - 1 : wi));
        }
#pragma unroll
        for (int nf = 0; nf < 4; ++nf) {
            int wj = wpos[b * NN + jh * 64 + nf * 16 + la];
            float vj = (wj != -1) ? 1.f : 0.f;
            float wjf = (float)(wj < 0 ? 0 : (wj > LL - 1 ? LL - 1 : wj));
#pragma unroll
            for (int r = 0; r < 4; ++r) {
                float sim = (acc[g][nf][r] + 1.f) * 0.5f;
                float ts  = 1.f - fabsf(wif[r] - wjf) * (1.f / (float)LL);
                float m2  = vi[r] * vj;
                float df  = m2 * (sim - ts);
                csum += df * df;
                msum += m2;
            }
        }
    }
    csum = breduce_sum<256>(csum, red);
    msum = breduce_sum<256>(msum, red);
    if (tid == 0) { rel_part[blk] = csum; vm2_part[blk] = msum; }
}

// ---------------------------------------------------------------------------
// MERGED: logits GEMM (blocks 0..255) + rel Gram (blocks 256..511)
// ---------------------------------------------------------------------------
__global__ __launch_bounds__(256)
void logits_rel_kernel(const u16* __restrict__ rnb, const u16* __restrict__ clipb,
                       const float* __restrict__ zbias, float* __restrict__ logits,
                       const int* __restrict__ wpos,
                       float* __restrict__ relp, float* __restrict__ vmp) {
    __shared__ __align__(16) u16 pool[4 * 128 * 64];   // 64 KB
    const int bid = blockIdx.x;
    if (bid < 256) {
        const int lin = (bid & 7) * 32 + (bid >> 3);
        const int m0 = (lin >> 1) * 128, n0 = (lin & 1) * 128;
        gemm_tile<0, 0, 0>(m0, n0, rnb, nullptr, nullptr, clipb, zbias,
                           logits, 256, DD, nullptr, pool, pool + 2 * 8192);
    } else {
        rel_tile(bid - 256, rnb, wpos, relp, vmp, pool);
    }
}

// ---------------------------------------------------------------------------
// MFMA attention (unchanged)
// ---------------------------------------------------------------------------
__global__ __launch_bounds__(512)
void attn_mfma_kernel(const u16* __restrict__ qp, const u16* __restrict__ kvb,
                      u16* __restrict__ ao) {
    __shared__ __align__(16) u16 K_lds[128 * 96];
    __shared__ __align__(16) u16 Vt_lds[96 * 128];
    __shared__ __align__(16) u16 P_lds[128 * 128];
    const int bh = blockIdx.x;
    const int b = bh >> 3, h = bh & 7;
    const int tid = threadIdx.x;
    const int l = tid & 63, wv = tid >> 6;
    const int la = l & 15, lg = l >> 4;
    const float scale = 0.10206207261596575f;

    const size_t qbase  = ((size_t)b * NN) * DD + h * HDh;
    const size_t kvbase = ((size_t)b * NN) * KVLD + h * HDh;

#pragma unroll
    for (int i = 0; i < 3; ++i) {
        int f = i * 8192 + wv * 1024 + l * 16;
        int row = f / 192;
        int inner = f - row * 192;
        gload16((const char*)(kvb + kvbase + (size_t)row * KVLD) + inner,
                (char*)K_lds + f);
    }

    uint4 vchunk[3]; int vkey[3], vd0[3];
#pragma unroll
    for (int i = 0; i < 3; ++i) {
        int c = tid + i * 512;
        int key = c / 12, dc = c - key * 12;
        vkey[i] = key; vd0[i] = dc * 8;
        vchunk[i] = *(const uint4*)(kvb + kvbase + (size_t)key * KVLD + DD + dc * 8);
    }

    const int q0 = wv * 16;
    s16x8 qf[3];
#pragma unroll
    for (int kt = 0; kt < 3; ++kt)
        qf[kt] = *(const s16x8*)(qp + qbase + (size_t)(q0 + la) * DD + kt * 32 + lg * 8);

#pragma unroll
    for (int i = 0; i < 3; ++i) {
        const u16* e = (const u16*)&vchunk[i];
#pragma unroll
        for (int j = 0; j < 8; ++j) {
            int d = vd0[i] + j;
            int byte = ((d * 128 + vkey[i]) * 2) ^ ((d & 7) << 4);
            *(u16*)((char*)Vt_lds + byte) = e[j];
        }
    }
    __syncthreads();

    f32x4 sacc[8] = {};
#pragma unroll
    for (int kt = 0; kt < 3; ++kt) {
#pragma unroll
        for (int nf = 0; nf < 8; ++nf) {
            s16x8 bfr = *(const s16x8*)(K_lds + (nf * 16 + la) * 96 + kt * 32 + lg * 8);
            sacc[nf] = __builtin_amdgcn_mfma_f32_16x16x32_bf16(qf[kt], bfr, sacc[nf], 0, 0, 0);
        }
    }

#pragma unroll
    for (int r = 0; r < 4; ++r) {
        float m = -1e30f;
#pragma unroll
        for (int nf = 0; nf < 8; ++nf) m = fmaxf(m, sacc[nf][r]);
#pragma unroll
        for (int o = 8; o > 0; o >>= 1) m = fmaxf(m, __shfl_xor(m, o, 64));
        m *= scale;
        float p[8]; float s = 0.f;
#pragma unroll
        for (int nf = 0; nf < 8; ++nf) { p[nf] = expf(sacc[nf][r] * scale - m); s += p[nf]; }
#pragma unroll
        for (int o = 8; o > 0; o >>= 1) s += __shfl_xor(s, o, 64);
        const float inv = 1.f / s;
        const int q = q0 + lg * 4 + r;
#pragma unroll
        for (int nf = 0; nf < 8; ++nf) {
            int byte = ((q * 128 + nf * 16 + la) * 2) ^ ((q & 7) << 4);
            *(u16*)((char*)P_lds + byte) = f2bf(p[nf] * inv);
        }
    }
    __syncthreads();

    f32x4 oacc[6] = {};
#pragma unroll
    for (int kk = 0; kk < 4; ++kk) {
        const int qrow = q0 + la;
        int abyte = ((qrow * 128 + kk * 32 + lg * 8) * 2) ^ ((qrow & 7) << 4);
        s16x8 af = *(const s16x8*)((char*)P_lds + abyte);
#pragma unroll
        for (int nf = 0; nf < 6; ++nf) {
            const int d = nf * 16 + la;
            int bbyte = ((d * 128 + kk * 32 + lg * 8) * 2) ^ ((d & 7) << 4);
            s16x8 bfr = *(const s16x8*)((char*)Vt_lds + bbyte);
            oacc[nf] = __builtin_amdgcn_mfma_f32_16x16x32_bf16(af, bfr, oacc[nf], 0, 0, 0);
        }
    }

#pragma unroll
    for (int nf = 0; nf < 6; ++nf) {
#pragma unroll
        for (int r = 0; r < 4; ++r) {
            const int q = q0 + lg * 4 + r;
            ao[qbase + (size_t)q * DD + nf * 16 + la] = f2bf(oacc[nf][r]);
        }
    }
}

// ---------------------------------------------------------------------------
// x = layernorm(q + attn_out)*vf -> bf16
// ---------------------------------------------------------------------------
__global__ __launch_bounds__(256)
void ln768_kernel(const u16* __restrict__ qb, const u16* __restrict__ at,
                  const int* __restrict__ wpos, const float* __restrict__ g,
                  const float* __restrict__ bta, u16* __restrict__ xout) {
    __shared__ float red[256];
    const int r = blockIdx.x, tid = threadIdx.x;
    const float vf = (wpos[r] != -1) ? 1.f : 0.f;
    float t[3]; float s = 0.f, q = 0.f;
#pragma unroll
    for (int j = 0; j < 3; ++j) {
        int d = tid + j * 256;
        t[j] = bf2f(qb[(size_t)r * DD + d]) + bf2f(at[(size_t)r * DD + d]);
        s += t[j];
        q = fmaf(t[j], t[j], q);
    }
    s = breduce_sum<256>(s, red);
    q = breduce_sum<256>(q, red);
    float mean = s * (1.f / DD);
    float var  = q * (1.f / DD) - mean * mean;
    float inv  = 1.f / sqrtf(var + 1e-5f);
#pragma unroll
    for (int j = 0; j < 3; ++j) {
        int d = tid + j * 256;
        xout[(size_t)r * DD + d] = f2bf(((t[j] - mean) * inv * g[d] + bta[d]) * vf);
    }
}

// ---------------------------------------------------------------------------
// h = layernorm(gelu(g1)) -> bf16
// ---------------------------------------------------------------------------
__global__ __launch_bounds__(256)
void ln256_gelu_kernel(const u16* __restrict__ g1, const float* __restrict__ lg,
                       const float* __restrict__ lb, u16* __restrict__ hout) {
    __shared__ float red[256];
    const int r = blockIdx.x, tid = threadIdx.x;
    float v  = bf2f(g1[(size_t)r * HIDN + tid]);
    float ge = 0.5f * v * (1.f + erff(v * 0.7071067811865475f));
    float s = breduce_sum<256>(ge, red);
    float q = breduce_sum<256>(ge * ge, red);
    float mean = s * (1.f / HIDN);
    float var  = q * (1.f / HIDN) - mean * mean;
    float inv  = 1.f / sqrtf(var + 1e-5f);
    hout[(size_t)r * HIDN + tid] = f2bf((ge - mean) * inv * lg[tid] + lb[tid]);
}

// ---------------------------------------------------------------------------
// MERGED: norm_rnb (blocks 0..16383) + emb full write (blocks 16384..48127)
// ---------------------------------------------------------------------------
__global__ __launch_bounds__(256)
void norm_emb_kernel(const u16* __restrict__ ropeb, const float* __restrict__ pe,
                     const int* __restrict__ wpos, u16* __restrict__ rnb,
                     float* __restrict__ emb) {
    __shared__ float red[256];
    const int bid = blockIdx.x;
    const int tid = threadIdx.x;
    if (bid < MROWS) {
        const int r = bid;
        float t[3]; float q = 0.f;
#pragma unroll
        for (int j = 0; j < 3; ++j) {
            t[j] = bf2f(ropeb[(size_t)r * DD + tid + j * 256]);
            q = fmaf(t[j], t[j], q);
        }
        q = breduce_sum<256>(q, red);
        float inv = 1.f / fmaxf(sqrtf(q), 1e-12f);
#pragma unroll
        for (int j = 0; j < 3; ++j)
            rnb[(size_t)r * DD + tid + j * 256] = f2bf(t[j] * inv);
    } else {
        const int bl = bid - MROWS;
        const int b = bl / LL, l = bl - b * LL;
        const int* wp = wpos + b * NN;
        int lo = 0, hi = NN - 1, found = -1;
        while (lo <= hi) {
            int mid = (lo + hi) >> 1;
            int v = wp[mid];
            if (v == l) { found = mid; break; }
            if (v < l) lo = mid + 1; else hi = mid - 1;
        }
        float* dst = emb + (size_t)bl * DD;
        if (found >= 0) {
            const u16* rr = ropeb + (size_t)(b * NN + found) * DD;
#pragma unroll
            for (int j = 0; j < 3; ++j) {
                int d = tid + j * 256;
                dst[d] = 0.8f * pe[(size_t)l * DD + d] + 0.2f * bf2f(rr[d]);
            }
        } else {
#pragma unroll
            for (int j = 0; j < 3; ++j)
                dst[tid + j * 256] = 0.f;
        }
    }
}

// ---------------------------------------------------------------------------
// KL from precomputed logits. One WAVE per row, 4 rows/block.
// ---------------------------------------------------------------------------
__global__ __launch_bounds__(256)
void kl_lite_kernel(const float* __restrict__ logits, const int* __restrict__ wpos,
                    const float* __restrict__ pos_temp, float* __restrict__ klp) {
    const int row = blockIdx.x * 4 + (threadIdx.x >> 6);
    const int l = threadIdx.x & 63;
    const float invt = 1.f / fmaxf(pos_temp[0], 0.001f);
    const float* lrow = logits + (size_t)row * 256;

    float lg[4];
#pragma unroll
    for (int q = 0; q < 4; ++q) {
        int c = l + q * 64;
        lg[q] = (c < LL) ? lrow[c] * invt : -1e30f;
    }
    float m = fmaxf(fmaxf(lg[0], lg[1]), fmaxf(lg[2], lg[3]));
#pragma unroll
    for (int o = 32; o > 0; o >>= 1) m = fmaxf(m, __shfl_xor(m, o, 64));

    float S = 0.f;
#pragma unroll
    for (int q = 0; q < 4; ++q) S += expf(lg[q] - m);
#pragma unroll
    for (int o = 32; o > 0; o >>= 1) S += __shfl_xor(S, o, 64);
    const float logZ = m + logf(S);

    const int wr = wpos[row];
    const bool valid = (wr != -1);
    const int wp = wr < 0 ? 0 : (wr > LL - 1 ? LL - 1 : wr);

    float targ[4]; float tsum = 0.f;
#pragma unroll
    for (int q = 0; q < 4; ++q) {
        int c = l + q * 64;
        float dl = (float)c - (float)wp;
        targ[q] = (c < LL) ? expf(-dl * dl * 0.125f) : 0.f;
        tsum += targ[q];
    }
#pragma unroll
    for (int o = 32; o > 0; o >>= 1) tsum += __shfl_xor(tsum, o, 64);
    const float tden = 1.f / (tsum + 1e-12f);

    float c_ = 0.f;
#pragma unroll
    for (int q = 0; q < 4; ++q) {
        float tn = targ[q] * tden;
        if (valid && tn > 0.f) c_ += tn * (logf(tn) - (lg[q] - logZ));
    }
#pragma unroll
    for (int o = 32; o > 0; o >>= 1) c_ += __shfl_xor(c_, o, 64);
    if (l == 0) klp[row] = c_;
}

// ---------------------------------------------------------------------------
// Final deterministic fp64 reduction
// ---------------------------------------------------------------------------
__global__ __launch_bounds__(256)
void final_kernel(const float* __restrict__ klp, const float* __restrict__ relp,
                  const float* __restrict__ vmp, const int* __restrict__ wpos,
                  float* __restrict__ outs) {
    __shared__ double rd[256];
    const int tid = threadIdx.x;
    double kl = 0.0, rel = 0.0, vm = 0.0, nv = 0.0;
    for (int r = tid; r < MROWS; r += 256) {
        kl += (double)klp[r];
        nv += (wpos[r] != -1) ? 1.0 : 0.0;
    }
    if (tid < 256) {
        rel += (double)relp[tid];
        vm  += (double)vmp[tid];
    }
    kl  = breduce_sum_d256(kl, rd);
    rel = breduce_sum_d256(rel, rd);
    vm  = breduce_sum_d256(vm, rd);
    nv  = breduce_sum_d256(nv, rd);
    if (tid == 0) {
        float klf  = (float)(kl / (nv + 1e-12));
        float relf = (float)(rel / (vm + 1e-12));
        outs[0] = klf + 0.5f * relf;
        outs[1] = klf;
        outs[2] = relf;
    }
}

// ---------------------------------------------------------------------------
extern "C" void kernel_launch(void* const* d_in, const int* in_sizes, int n_in,
                              void* d_out, int out_size, void* d_ws, size_t ws_size,
                              hipStream_t stream) {
    (void)in_sizes; (void)n_in; (void)ws_size; (void)out_size;

    const float* word_feat = (const float*)d_in[0];
    const float* text      = (const float*)d_in[1];
    const int*   wpos      = (const int*)d_in[2];
    const float* ctx_W     = (const float*)d_in[3];
    const float* ctx_b     = (const float*)d_in[4];
    const float* in_W      = (const float*)d_in[5];
    const float* in_b      = (const float*)d_in[6];
    const float* out_W     = (const float*)d_in[7];
    const float* out_b     = (const float*)d_in[8];
    const float* cn_g      = (const float*)d_in[9];
    const float* cn_b      = (const float*)d_in[10];
    const float* r1_W      = (const float*)d_in[11];
    const float* r1_b      = (const float*)d_in[12];
    const float* ln_g      = (const float*)d_in[13];
    const float* ln_b      = (const float*)d_in[14];
    const float* r2_W      = (const float*)d_in[15];
    const float* r2_b      = (const float*)d_in[16];
    const float* pos_emb   = (const float*)d_in[17];
    const float* pos_temp  = (const float*)d_in[18];

    char* W = (char*)d_ws;
    // --- weight/partials area [0, 12MB) ---
    u16*   ctx_Wt = (u16*)(W);
    u16*   in_Wt  = ctx_Wt + (size_t)768 * 2304;
    u16*   out_Wt = in_Wt  + (size_t)2304 * 768;
    u16*   r1_Wt  = out_Wt + (size_t)768 * 768;
    u16*   r2_Wt  = r1_Wt  + (size_t)256 * 768;
    u16*   clipb  = r2_Wt + (size_t)768 * 256;          // [256][768] bf16
    int*   cposb  = (int*)(clipb + (size_t)256 * DD);
    float* klp    = (float*)(cposb + MROWS);
    float* relp   = klp + MROWS;
    float* vmp    = relp + 256;
    float* zbias  = vmp + 256;                           // 256 zero floats
    // --- big regions (lifetimes audited) ---
    u16*   textb  = (u16*)(W + (size_t)12 * MB_);   // 12-58.5, dead after ctx GEMM
    u16*   atoutb = textb;                           // reuse 12-36
    float* logits = (float*)(W + (size_t)12 * MB_);  // reuse 12-28
    u16*   xb     = (u16*)(W + (size_t)36 * MB_);   // 36-60
    u16*   qb     = (u16*)(W + (size_t)60 * MB_);   // 60-84
    u16*   ctxa   = (u16*)(W + (size_t)86 * MB_);   // 86-110
    u16*   aob    = ctxa;
    u16*   rnb    = ctxa;
    u16*   qpb    = (u16*)(W + (size_t)112 * MB_);  // 112-136
    u16*   g1b    = (u16*)(W + (size_t)112 * MB_);  // reuse 112-120
    u16*   hb     = (u16*)(W + (size_t)128 * MB_);  // 128-136.4
    u16*   kvb    = (u16*)(W + (size_t)138 * MB_);  // 138-186
    u16*   ropeb  = kvb;                             // reuse 138-162

    dim3 blk(256);

    // 1. prep: transposes + clip_n + elementwise + cpos + zbias
    prep_all_kernel<<<dim3(4416 + 256 + 2048), blk, 0, stream>>>(
        ctx_W, ctx_Wt, in_W, in_Wt, out_W, out_Wt, r1_W, r1_Wt, r2_W, r2_Wt,
        text, textb, word_feat, qb, wpos, cposb, pos_emb, clipb, zbias);

    dim3 g768(6, 128);
    dim3 g1536(12, 128);

    // 2. MERGED ctx GEMM + qp GEMM (independent)
    gemm_ctx_qp_kernel<<<dim3(1536), blk, 0, stream>>>(
        textb, cposb, ctx_Wt, ctx_b, ctxa, qb, in_Wt, in_b, qpb, wpos);
    // 3. fused kp|vp
    gemm_bt<0, 1, 0><<<g1536, blk, 0, stream>>>(
        ctxa, nullptr, nullptr, in_Wt + (size_t)768 * 768, in_b + DD, kvb, KVLD, DD, nullptr);
    // 4. MFMA attention -> ao (overwrites ctxa)
    attn_mfma_kernel<<<dim3(BB * HH), dim3(512), 0, stream>>>(qpb, kvb, aob);
    // 5. attn_out = ao @ out_W + out_b
    gemm_bt<0, 1, 0><<<g768, blk, 0, stream>>>(
        aob, nullptr, nullptr, out_Wt, out_b, atoutb, DD, DD, nullptr);
    // 6. x = LN(q + attn_out)*vf
    ln768_kernel<<<dim3(MROWS), blk, 0, stream>>>(qb, atoutb, wpos, cn_g, cn_b, xb);
    // 7. g1 = x @ r1_W + r1_b -> bf16
    gemm_bt<0, 1, 0><<<dim3(2, 128), blk, 0, stream>>>(
        xb, nullptr, nullptr, r1_Wt, r1_b, g1b, HIDN, DD, nullptr);
    // 8. h = LN(gelu(g1))
    ln256_gelu_kernel<<<dim3(MROWS), blk, 0, stream>>>(g1b, ln_g, ln_b, hb);
    // 9. rope = h @ r2_W + r2_b -> bf16
    gemm_bt<0, 1, 0><<<g768, blk, 0, stream>>>(
        hb, nullptr, nullptr, r2_Wt, r2_b, ropeb, DD, HIDN, nullptr);
    // 10. MERGED norm_rnb + emb full write (both read ropeb only)
    norm_emb_kernel<<<dim3(MROWS + BB * LL), blk, 0, stream>>>(
        ropeb, pos_emb, wpos, rnb, (float*)d_out);
    // 11. MERGED logits GEMM + rel Gram (both read rnb only)
    logits_rel_kernel<<<dim3(512), blk, 0, stream>>>(
        rnb, clipb, zbias, logits, wpos, relp, vmp);
    // 12. KL from logits
    kl_lite_kernel<<<dim3(MROWS / 4), blk, 0, stream>>>(logits, wpos, pos_temp, klp);
    // 13. scalars
    final_kernel<<<dim3(1), blk, 0, stream>>>(
        klp, relp, vmp, wpos, (float*)d_out + (size_t)BB * LL * DD);
}